// Round 4
// baseline (212.022 us; speedup 1.0000x reference)
//
#include <hip/hip_runtime.h>

#define FH 64
#define FW 64
#define NWF 33
#define NBIN (FH*NWF)      // 2112
#define NIMG 4096          // 4 * 32 * 32
#define PI2 6.283185307179586f

typedef unsigned short u16;
typedef unsigned int u32;
typedef __attribute__((ext_vector_type(8))) short bf16x8;
typedef __attribute__((ext_vector_type(4))) float f32x4;
typedef __attribute__((ext_vector_type(4))) int   i32x4;

__device__ __forceinline__ int brev6(int v) { return (int)(__brev((unsigned)v) >> 26); }

__device__ __forceinline__ u16 f2bf(float f) {
    unsigned u = __float_as_uint(f);
    unsigned r = (u + 0x7FFFu + ((u >> 16) & 1u)) >> 16;   // RNE
    return (u16)r;
}

// ---- in-register 64-pt radix-2 DIF FFT across one wave (lane = point) ----
// Output: lane p holds X[brev6(p)]. Twiddles/signs hoisted per-lane.
struct TwSet { float2 tw[6]; float sg[6]; };

__device__ __forceinline__ TwSet make_tw(int lane, float dir) {
    TwSet t;
    #pragma unroll
    for (int s = 0; s < 6; ++s) {
        int m = 32 >> s;
        int jj = lane & (m - 1);
        float ang = dir * PI2 * (float)(jj << s) / 64.0f;
        bool hi = (lane & m) != 0;
        t.sg[s] = hi ? -1.f : 1.f;
        t.tw[s].x = hi ? cosf(ang) : 1.f;
        t.tw[s].y = hi ? sinf(ang) : 0.f;
    }
    return t;
}

__device__ __forceinline__ float2 fft64(float2 z, const TwSet& t) {
    #pragma unroll
    for (int s = 0; s < 6; ++s) {
        const int m = 32 >> s;
        float ox = __shfl_xor(z.x, m, 64);
        float oy = __shfl_xor(z.y, m, 64);
        float px = fmaf(t.sg[s], z.x, ox);
        float py = fmaf(t.sg[s], z.y, oy);
        z.x = px*t.tw[s].x - py*t.tw[s].y;
        z.y = px*t.tw[s].y + py*t.tw[s].x;
    }
    return z;
}

// ---------------- forward rfft2: one block per image, shuffle FFT ----------------
// Writes Xs as packed bf16 (re lo, im hi) u32 per bin: Xs[img][bin].
__global__ __launch_bounds__(256) void fft_fwd_kernel(const float* __restrict__ x,
                                                      u32* __restrict__ Xs)
{
    const int img = blockIdx.x;        // q*1024 + b*32 + i
    const int p  = img >> 10;
    const int b  = (img >> 5) & 31;
    const int ci = img & 31;
    const float* __restrict__ src = x + ((size_t)b*128 + (size_t)p*32 + ci) * (FH*FW);

    __shared__ float2 zmat[32*65];     // row spectra (bitrev positions), padded
    __shared__ u32    sbin[NBIN];

    const int tid  = threadIdx.x;
    const int lane = tid & 63;
    const int wid  = tid >> 6;
    const TwSet T = make_tw(lane, -1.f);

    // row pass: pack rows (2r, 2r+1) as complex, FFT in regs
    #pragma unroll
    for (int j = 0; j < 8; ++j) {
        const int r = wid*8 + j;
        float a = src[r*128 + lane];
        float bb = src[r*128 + 64 + lane];
        float2 z = fft64(make_float2(a, bb), T);
        zmat[r*65 + lane] = z;         // position p holds Z[brev6(p)]
    }
    __syncthreads();

    // column pass: unpack A/B, FFT along h, store spatial-corrected packed bf16
    for (int k = wid; k < 33; k += 4) {
        const int c1 = brev6(k), c2 = brev6((64 - k) & 63);
        const int r = lane >> 1;
        float2 Zp = zmat[r*65 + c1];
        float2 Zq = zmat[r*65 + c2];
        float2 A = make_float2(0.5f*(Zp.x + Zq.x), 0.5f*(Zp.y - Zq.y));
        float2 B = make_float2(0.5f*(Zp.y + Zq.y), -0.5f*(Zp.x - Zq.x));
        float2 v = (lane & 1) ? B : A;
        v = fft64(v, T);
        sbin[brev6(lane)*33 + k] = (u32)f2bf(v.x) | ((u32)f2bf(v.y) << 16);
    }
    __syncthreads();

    u32* __restrict__ dst = Xs + (size_t)img * NBIN;
    for (int t = tid; t < NBIN; t += 256) dst[t] = dst[t]*0 + sbin[t];
}

// ---------------- transpose X: [img][bin] u32 -> [bin][q][ri][b][i] bf16 ----------------
__global__ __launch_bounds__(256) void xpose_x_kernel(const u32* __restrict__ Xs,
                                                      u32* __restrict__ XT)
{
    const int g    = blockIdx.x;        // q*32 + b
    const int bin0 = blockIdx.y * 32;
    __shared__ u32 tile[32][33];
    const int tid = threadIdx.x;
    #pragma unroll
    for (int it = 0; it < 4; ++it) {
        int e = tid + it*256;
        int imgL = e >> 5, binL = e & 31;
        tile[imgL][binL] = Xs[(size_t)(g*32 + imgL) * NBIN + bin0 + binL];
    }
    __syncthreads();
    const int q = g >> 5, b = g & 31;
    #pragma unroll
    for (int it = 0; it < 2; ++it) {
        int e = tid + it*256;          // 512 tasks: [binL][i-pair]
        int binL = e >> 4, pr = e & 15;
        u32 v0 = tile[pr*2][binL], v1 = tile[pr*2 + 1][binL];
        u32 re = (v0 & 0xFFFFu) | (v1 << 16);
        u32 im = (v0 >> 16) | (v1 & 0xFFFF0000u);
        size_t base = ((size_t)(bin0 + binL)*8 + q*2) * 512 + b*16 + pr;  // u32 units
        XT[base]       = re;
        XT[base + 512] = im;
    }
}

// ---------------- transpose W: [i][o][bin] f32 -> [bin][p][ri][o][i] bf16 ----------------
__global__ __launch_bounds__(256) void prep_w_kernel(
    const float* __restrict__ s0, const float* __restrict__ s1,
    const float* __restrict__ s2, const float* __restrict__ s3,
    const float* __restrict__ s4, const float* __restrict__ s5,
    const float* __restrict__ s6, const float* __restrict__ s7,
    u16* __restrict__ WT)
{
    const int a = blockIdx.y;           // ri*4 + p
    const int p = a & 3, ri = a >> 2;
    const float* __restrict__ src =
        (a==0)?s0:(a==1)?s1:(a==2)?s2:(a==3)?s3:(a==4)?s4:(a==5)?s5:(a==6)?s6:s7;
    const int bin0 = blockIdx.x * 16;
    __shared__ u16 lds[16][1032];
    const int tid = threadIdx.x;
    for (int it = 0; it < 64; ++it) {
        int e = tid + it*256;
        int io = e >> 4, binL = e & 15;
        float v = src[(size_t)io * NBIN + bin0 + binL];
        int i = io >> 5, o = io & 31;
        lds[binL][o*32 + i] = f2bf(v);
    }
    __syncthreads();
    #pragma unroll
    for (int it = 0; it < 8; ++it) {
        int c = tid + it*256;
        int binL = c >> 7, ch = c & 127;
        bf16x8 v = *(const bf16x8*)&lds[binL][ch*8];
        size_t dst = ((size_t)((bin0 + binL)*4 + p)*2 + ri)*1024 + ch*8;
        *(bf16x8*)(WT + dst) = v;
    }
}

// ---------------- per-bin quaternion contraction via MFMA ----------------
// Writes PT[img][bin] (transposed) so fft_inv reads coalesced rows.
__global__ __launch_bounds__(256) void contract_kernel(
    const u16* __restrict__ XT, const u16* __restrict__ WT,
    float2* __restrict__ PT)
{
    const int bid  = blockIdx.x;
    const int bin  = (bid & 7) * (NBIN/8) + (bid >> 3);   // chunked XCD swizzle
    const int wid  = threadIdx.x >> 6;
    const int lane = threadIdx.x & 63;
    const int bh = wid >> 1, oh = wid & 1;
    const int row = lane & 15, kg = lane >> 4;

    const u16* __restrict__ xb = XT + (size_t)bin * 8192;
    const u16* __restrict__ wb = WT + (size_t)bin * 8192;

    bf16x8 ax[4][2];
    #pragma unroll
    for (int q = 0; q < 4; ++q)
        #pragma unroll
        for (int ri = 0; ri < 2; ++ri)
            ax[q][ri] = *(const bf16x8*)(xb + ((q*2 + ri)*32 + bh*16 + row)*32 + kg*8);

    bf16x8 wpos[4][2], wneg[4][2];
    #pragma unroll
    for (int p = 0; p < 4; ++p)
        #pragma unroll
        for (int ri = 0; ri < 2; ++ri) {
            bf16x8 w = *(const bf16x8*)(wb + ((p*2 + ri)*32 + oh*16 + row)*32 + kg*8);
            wpos[p][ri] = w;
            i32x4 t = __builtin_bit_cast(i32x4, w);
            t ^= (int)0x80008000;
            wneg[p][ri] = __builtin_bit_cast(bf16x8, t);
        }

    f32x4 acc[4][2];
    #pragma unroll
    for (int c = 0; c < 4; ++c)
        #pragma unroll
        for (int ri = 0; ri < 2; ++ri)
            acc[c][ri] = (f32x4){0.f, 0.f, 0.f, 0.f};

    constexpr int PI_[4][4] = {{0,1,2,3},{1,0,3,2},{2,3,0,1},{3,2,1,0}};
    constexpr int SG_[4][4] = {{1,-1,-1,-1},{1,1,-1,1},{1,1,1,-1},{1,-1,1,1}};
    #pragma unroll
    for (int c = 0; c < 4; ++c)
        #pragma unroll
        for (int q = 0; q < 4; ++q) {
            const int  p   = PI_[c][q];
            const bool pos = SG_[c][q] > 0;
            bf16x8 wr_s = pos ? wpos[p][0] : wneg[p][0];
            bf16x8 wi_s = pos ? wpos[p][1] : wneg[p][1];
            bf16x8 wi_m = pos ? wneg[p][1] : wpos[p][1];
            acc[c][0] = __builtin_amdgcn_mfma_f32_16x16x32_bf16(ax[q][0], wr_s, acc[c][0], 0, 0, 0);
            acc[c][0] = __builtin_amdgcn_mfma_f32_16x16x32_bf16(ax[q][1], wi_m, acc[c][0], 0, 0, 0);
            acc[c][1] = __builtin_amdgcn_mfma_f32_16x16x32_bf16(ax[q][1], wr_s, acc[c][1], 0, 0, 0);
            acc[c][1] = __builtin_amdgcn_mfma_f32_16x16x32_bf16(ax[q][0], wi_s, acc[c][1], 0, 0, 0);
        }

    // D layout: col(o) = lane&15, row(b) = (lane>>4)*4 + reg
    // PT[img][bin], img = c*1024 + b*32 + o  (8 sibling bins share a 64B line;
    // bin swizzle keeps them on one XCD so L2 write-combines full lines)
    #pragma unroll
    for (int c = 0; c < 4; ++c)
        #pragma unroll
        for (int r = 0; r < 4; ++r) {
            int b_ = bh*16 + kg*4 + r;
            int o  = oh*16 + row;
            PT[((size_t)(c*1024 + b_*32 + o))*NBIN + bin] = make_float2(acc[c][0][r], acc[c][1][r]);
        }
}

// ---------------- inverse rfft2: one block per output image, shuffle FFT ----------------
__global__ __launch_bounds__(256) void fft_inv_kernel(const float2* __restrict__ PT,
                                                      float* __restrict__ out)
{
    const int bid = blockIdx.x;
    const int img = ((bid & 7) << 9) + (bid >> 3);   // chunked XCD swizzle
    const int p  = img >> 10;
    const int b  = (img >> 5) & 31;
    const int oc = img & 31;

    __shared__ float2 sbin[NBIN];      // spectra; reused as zout planes at the end
    __shared__ float2 zrow[32*64];

    const int tid  = threadIdx.x;
    const int lane = tid & 63;
    const int wid  = tid >> 6;
    const TwSet T = make_tw(lane, 1.f);

    // coalesced row read: PT[img][0..2112)
    const float2* __restrict__ srcP = PT + (size_t)img * NBIN;
    for (int t = tid; t < NBIN; t += 256) sbin[t] = srcP[t];
    __syncthreads();

    // inverse FFT along h per k-column, in place, spatial-corrected store
    for (int k = wid; k < 33; k += 4) {
        float2 v = sbin[lane*33 + k];
        v = fft64(v, T);
        sbin[brev6(lane)*33 + k] = v;
    }
    __syncthreads();

    // build packed full spectra Z = A + iB for row pairs (2r, 2r+1)
    for (int t = tid; t < 2048; t += 256) {
        int r = t >> 6, kp = t & 63;
        int m = (kp <= 32) ? kp : 64 - kp;
        float2 A = sbin[(2*r)*33 + m];
        float2 B = sbin[(2*r+1)*33 + m];
        if (m == 0 || m == 32) { A.y = 0.f; B.y = 0.f; }
        float sgn = (kp <= 32) ? 1.f : -1.f;
        A.y *= sgn; B.y *= sgn;
        zrow[r*64 + kp] = make_float2(A.x - B.y, A.y + B.x);
    }
    __syncthreads();

    // inverse FFT along w per packed row; split re/im planes (b32, 2-way max)
    float* zoutRe = (float*)sbin;
    float* zoutIm = zoutRe + 2048;
    #pragma unroll
    for (int j = 0; j < 8; ++j) {
        const int r = wid*8 + j;
        float2 v = fft64(zrow[r*64 + lane], T);
        const int wsp = brev6(lane);
        zoutRe[r*64 + wsp] = v.x;      // spatial row 2r
        zoutIm[r*64 + wsp] = v.y;      // spatial row 2r+1
    }
    __syncthreads();

    const float scale = 1.0f / 4096.0f;
    float* __restrict__ dst = out + ((size_t)b*128 + (size_t)p*32 + oc) * (FH*FW);
    for (int t = tid; t < FH*FW; t += 256) {
        int row = t >> 6, w = t & 63, r = row >> 1;
        float v = (row & 1) ? zoutIm[r*64 + w] : zoutRe[r*64 + w];
        dst[t] = v * scale;
    }
}

extern "C" void kernel_launch(void* const* d_in, const int* in_sizes, int n_in,
                              void* d_out, int out_size, void* d_ws, size_t ws_size,
                              hipStream_t stream)
{
    const float* x   = (const float*)d_in[0];
    const float* krw = (const float*)d_in[1];
    const float* krx = (const float*)d_in[2];
    const float* kry = (const float*)d_in[3];
    const float* krz = (const float*)d_in[4];
    const float* kiw = (const float*)d_in[5];
    const float* kix = (const float*)d_in[6];
    const float* kiy = (const float*)d_in[7];
    const float* kiz = (const float*)d_in[8];

    // ws: [XT 34.6 MB][WT 34.6 MB][Xs_u32 34.6 MB / PT f32x2 69.2 MB aliased]
    u16* XT = (u16*)d_ws;
    u16* WT = XT + (size_t)NBIN*8192;
    u32* Xs = (u32*)(WT + (size_t)NBIN*8192);
    float2* PT = (float2*)Xs;                       // alias: Xs dead after xpose
    float* out = (float*)d_out;

    prep_w_kernel<<<dim3(NBIN/16, 8), 256, 0, stream>>>(krw, krx, kry, krz,
                                                        kiw, kix, kiy, kiz, WT);
    fft_fwd_kernel<<<dim3(NIMG), 256, 0, stream>>>(x, Xs);
    xpose_x_kernel<<<dim3(128, NBIN/32), 256, 0, stream>>>(Xs, (u32*)XT);
    contract_kernel<<<dim3(NBIN), 256, 0, stream>>>(XT, WT, PT);
    fft_inv_kernel<<<dim3(NIMG), 256, 0, stream>>>(PT, out);
}

// Round 5
// 179.230 us; speedup vs baseline: 1.1830x; 1.1830x over previous
//
#include <hip/hip_runtime.h>

#define FH 64
#define FW 64
#define NWF 33
#define NBIN (FH*NWF)      // 2112
#define NIMG 4096          // 4 * 32 * 32
#define PI2 6.283185307179586f
#define LSTR 67            // LDS float2 row stride (134 words, != 0 mod 32 banks)

typedef unsigned short u16;
typedef unsigned int u32;
typedef __attribute__((ext_vector_type(8))) short bf16x8;
typedef __attribute__((ext_vector_type(4))) float f32x4;
typedef __attribute__((ext_vector_type(4))) int   i32x4;

__device__ __forceinline__ u16 f2bf(float f) {
    unsigned u = __float_as_uint(f);
    unsigned r = (u + 0x7FFFu + ((u >> 16) & 1u)) >> 16;   // RNE
    return (u16)r;
}
__device__ __forceinline__ float2 upk(u32 v) {
    return make_float2(__uint_as_float(v << 16), __uint_as_float(v & 0xFFFF0000u));
}
__device__ __forceinline__ u32 pk(float2 v) {
    return (u32)f2bf(v.x) | ((u32)f2bf(v.y) << 16);
}
__device__ __forceinline__ float2 cadd(float2 a, float2 b){ return make_float2(a.x+b.x, a.y+b.y); }
__device__ __forceinline__ float2 csub(float2 a, float2 b){ return make_float2(a.x-b.x, a.y-b.y); }
__device__ __forceinline__ float2 cmul(float2 a, float2 b){
    return make_float2(a.x*b.x - a.y*b.y, a.x*b.y + a.y*b.x);
}
// multiply by (DIR<0 ? -i : +i)
template<int DIR> __device__ __forceinline__ float2 mulpmi(float2 a){
    return (DIR < 0) ? make_float2(a.y, -a.x) : make_float2(-a.y, a.x);
}

// 8-point DFT in registers, natural-order in/out. DIR=-1 fwd, +1 inv (unscaled).
template<int DIR> __device__ __forceinline__ void dft8(float2 v[8]) {
    const float s = 0.70710678118654752f;
    float2 u0=cadd(v[0],v[4]), u1=cadd(v[1],v[5]), u2=cadd(v[2],v[6]), u3=cadd(v[3],v[7]);
    float2 t0=csub(v[0],v[4]), t1=csub(v[1],v[5]), t2=csub(v[2],v[6]), t3=csub(v[3],v[7]);
    float2 w1, w3;
    if (DIR < 0) { w1 = make_float2(s*(t1.x+t1.y),  s*(t1.y-t1.x));
                   w3 = make_float2(s*(t3.y-t3.x), -s*(t3.x+t3.y)); }
    else         { w1 = make_float2(s*(t1.x-t1.y),  s*(t1.x+t1.y));
                   w3 = make_float2(-s*(t3.x+t3.y), s*(t3.x-t3.y)); }
    float2 w2 = mulpmi<DIR>(t2);
    float2 a0=cadd(u0,u2), a1=cadd(u1,u3), b0=csub(u0,u2), b1=mulpmi<DIR>(csub(u1,u3));
    float2 c0=cadd(t0,w2), c1=cadd(w1,w3), d0=csub(t0,w2), d1=mulpmi<DIR>(csub(w1,w3));
    v[0]=cadd(a0,a1); v[4]=csub(a0,a1);
    v[2]=cadd(b0,b1); v[6]=csub(b0,b1);
    v[1]=cadd(c0,c1); v[5]=csub(c0,c1);
    v[3]=cadd(d0,d1); v[7]=csub(d0,d1);
}

// ---------------- forward rfft2: one block per image, 8x8 register FFT ----------------
__global__ __launch_bounds__(256) void fft_fwd_kernel(const float* __restrict__ x,
                                                      u32* __restrict__ Xs)
{
    const int img = blockIdx.x;        // q*1024 + b*32 + i
    const int q  = img >> 10;
    const int b  = (img >> 5) & 31;
    const int ci = img & 31;
    const float* __restrict__ src = x + ((size_t)b*128 + (size_t)q*32 + ci) * (FH*FW);

    __shared__ float2 bufA[33*LSTR];   // staging floats / scolP
    __shared__ float2 bufB[33*LSTR];   // dft8-phase1 outputs
    __shared__ float2 bufC[32*LSTR];   // row spectra Z natural
    __shared__ u32    sbin[64*34];

    const int tid = threadIdx.x;
    const int g = tid >> 3, sub = tid & 7;
    float2 tw[8];
    #pragma unroll
    for (int j = 0; j < 8; ++j) {
        float sn, cs;
        __sincosf(-PI2 * (float)(sub*j) / 64.f, &sn, &cs);
        tw[j] = make_float2(cs, sn);
    }

    // stage image with per-row rotation rot(h) = 8h + 4*(h>>3), keeps float4 align
    float* simg = (float*)bufA;
    for (int t = tid; t < 1024; t += 256) {
        float4 v = ((const float4*)src)[t];
        int flat = t << 2, h = flat >> 6, w = flat & 63;
        int wr = (w + 8*h + 4*(h >> 3)) & 63;
        *(float4*)&simg[h*64 + wr] = v;
    }
    __syncthreads();

    // R1: packed row pair r=g, n1=sub: dft8 over n2 + twiddle
    {
        float2 v[8];
        const int h0 = 2*g, h1 = 2*g + 1;
        const int r0 = (8*h0 + 4*(h0 >> 3)) & 63, r1 = (8*h1 + 4*(h1 >> 3)) & 63;
        #pragma unroll
        for (int n2 = 0; n2 < 8; ++n2) {
            int w = sub + 8*n2;
            v[n2].x = simg[h0*64 + ((w + r0) & 63)];
            v[n2].y = simg[h1*64 + ((w + r1) & 63)];
        }
        dft8<-1>(v);
        #pragma unroll
        for (int k1 = 0; k1 < 8; ++k1)
            bufB[g*LSTR + sub*8 + k1] = cmul(v[k1], tw[k1]);
    }
    __syncthreads();

    // R2: r=g, k1=sub: dft8 over n1 -> Z[k1+8k2], natural store
    {
        float2 v[8];
        #pragma unroll
        for (int n1 = 0; n1 < 8; ++n1) v[n1] = bufB[g*LSTR + n1*8 + sub];
        dft8<-1>(v);
        #pragma unroll
        for (int k2 = 0; k2 < 8; ++k2) bufC[g*LSTR + sub + 8*k2] = v[k2];
    }
    __syncthreads();

    // unpack packed-row spectra -> column problems bufA[p=k][h]
    for (int e = tid; e < 2112; e += 256) {
        int p = e >> 6, h = e & 63, r = h >> 1;
        float2 Zp = bufC[r*LSTR + p];
        float2 Zq = bufC[r*LSTR + ((64 - p) & 63)];
        float2 val;
        if ((h & 1) == 0) val = make_float2(0.5f*(Zp.x + Zq.x), 0.5f*(Zp.y - Zq.y));
        else              val = make_float2(0.5f*(Zp.y + Zq.y), 0.5f*(Zq.x - Zp.x));
        bufA[p*LSTR + h] = val;
    }
    __syncthreads();

    // C1: column dft8 over m2 + twiddle (33 problems over 32 groups)
    for (int p = g; p < 33; p += 32) {
        float2 v[8];
        #pragma unroll
        for (int m2 = 0; m2 < 8; ++m2) v[m2] = bufA[p*LSTR + sub + 8*m2];
        dft8<-1>(v);
        #pragma unroll
        for (int j1 = 0; j1 < 8; ++j1)
            bufB[p*LSTR + sub*8 + j1] = cmul(v[j1], tw[j1]);
    }
    __syncthreads();

    // C2: dft8 over n1 -> final spectra at hf = j1+8j2, pack bf16
    for (int p = g; p < 33; p += 32) {
        float2 v[8];
        #pragma unroll
        for (int n1 = 0; n1 < 8; ++n1) v[n1] = bufB[p*LSTR + n1*8 + sub];
        dft8<-1>(v);
        #pragma unroll
        for (int j2 = 0; j2 < 8; ++j2)
            sbin[(sub + 8*j2)*34 + p] = pk(v[j2]);
    }
    __syncthreads();

    u32* __restrict__ dst = Xs + (size_t)img * NBIN;
    for (int t = tid; t < NBIN; t += 256) {
        int hf = t / 33, k = t - hf*33;
        dst[t] = sbin[hf*34 + k];
    }
}

// ---------------- transpose X: [img][bin] u32 -> [bin][q][ri][b][i] bf16 ----------------
__global__ __launch_bounds__(256) void xpose_x_kernel(const u32* __restrict__ Xs,
                                                      u32* __restrict__ XT)
{
    const int g    = blockIdx.x;        // q*32 + b
    const int bin0 = blockIdx.y * 32;
    __shared__ u32 tile[32][33];
    const int tid = threadIdx.x;
    #pragma unroll
    for (int it = 0; it < 4; ++it) {
        int e = tid + it*256;
        int imgL = e >> 5, binL = e & 31;
        tile[imgL][binL] = Xs[(size_t)(g*32 + imgL) * NBIN + bin0 + binL];
    }
    __syncthreads();
    const int q = g >> 5, b = g & 31;
    #pragma unroll
    for (int it = 0; it < 2; ++it) {
        int e = tid + it*256;          // 512 tasks: [binL][i-pair]
        int binL = e >> 4, pr = e & 15;
        u32 v0 = tile[pr*2][binL], v1 = tile[pr*2 + 1][binL];
        u32 re = (v0 & 0xFFFFu) | (v1 << 16);
        u32 im = (v0 >> 16) | (v1 & 0xFFFF0000u);
        size_t base = ((size_t)(bin0 + binL)*8 + q*2) * 512 + b*16 + pr;  // u32 units
        XT[base]       = re;
        XT[base + 512] = im;
    }
}

// ---------------- transpose W: [i][o][bin] f32 -> [bin][p][ri][o][i] bf16 ----------------
__global__ __launch_bounds__(256) void prep_w_kernel(
    const float* __restrict__ s0, const float* __restrict__ s1,
    const float* __restrict__ s2, const float* __restrict__ s3,
    const float* __restrict__ s4, const float* __restrict__ s5,
    const float* __restrict__ s6, const float* __restrict__ s7,
    u16* __restrict__ WT)
{
    const int a = blockIdx.y;           // ri*4 + p
    const int p = a & 3, ri = a >> 2;
    const float* __restrict__ src =
        (a==0)?s0:(a==1)?s1:(a==2)?s2:(a==3)?s3:(a==4)?s4:(a==5)?s5:(a==6)?s6:s7;
    const int bin0 = blockIdx.x * 16;
    __shared__ u16 lds[16][1032];
    const int tid = threadIdx.x;
    for (int it = 0; it < 64; ++it) {
        int e = tid + it*256;
        int io = e >> 4, binL = e & 15;
        float v = src[(size_t)io * NBIN + bin0 + binL];
        int i = io >> 5, o = io & 31;
        lds[binL][o*32 + i] = f2bf(v);
    }
    __syncthreads();
    #pragma unroll
    for (int it = 0; it < 8; ++it) {
        int c = tid + it*256;
        int binL = c >> 7, ch = c & 127;
        bf16x8 v = *(const bf16x8*)&lds[binL][ch*8];
        size_t dst = ((size_t)((bin0 + binL)*4 + p)*2 + ri)*1024 + ch*8;
        *(bf16x8*)(WT + dst) = v;
    }
}

// ---------------- per-bin quaternion contraction via MFMA ----------------
// Writes P[bin][c][b][o] packed bf16 u32, fully coalesced.
__global__ __launch_bounds__(256) void contract_kernel(
    const u16* __restrict__ XT, const u16* __restrict__ WT,
    u32* __restrict__ P)
{
    const int bid  = blockIdx.x;
    const int bin  = (bid & 7) * (NBIN/8) + (bid >> 3);   // chunked XCD swizzle
    const int wid  = threadIdx.x >> 6;
    const int lane = threadIdx.x & 63;
    const int bh = wid >> 1, oh = wid & 1;
    const int row = lane & 15, kg = lane >> 4;

    const u16* __restrict__ xb = XT + (size_t)bin * 8192;
    const u16* __restrict__ wb = WT + (size_t)bin * 8192;

    bf16x8 ax[4][2];
    #pragma unroll
    for (int q = 0; q < 4; ++q)
        #pragma unroll
        for (int ri = 0; ri < 2; ++ri)
            ax[q][ri] = *(const bf16x8*)(xb + ((q*2 + ri)*32 + bh*16 + row)*32 + kg*8);

    bf16x8 wpos[4][2], wneg[4][2];
    #pragma unroll
    for (int p = 0; p < 4; ++p)
        #pragma unroll
        for (int ri = 0; ri < 2; ++ri) {
            bf16x8 w = *(const bf16x8*)(wb + ((p*2 + ri)*32 + oh*16 + row)*32 + kg*8);
            wpos[p][ri] = w;
            i32x4 t = __builtin_bit_cast(i32x4, w);
            t ^= (int)0x80008000;
            wneg[p][ri] = __builtin_bit_cast(bf16x8, t);
        }

    f32x4 acc[4][2];
    #pragma unroll
    for (int c = 0; c < 4; ++c)
        #pragma unroll
        for (int ri = 0; ri < 2; ++ri)
            acc[c][ri] = (f32x4){0.f, 0.f, 0.f, 0.f};

    constexpr int PI_[4][4] = {{0,1,2,3},{1,0,3,2},{2,3,0,1},{3,2,1,0}};
    constexpr int SG_[4][4] = {{1,-1,-1,-1},{1,1,-1,1},{1,1,1,-1},{1,-1,1,1}};
    #pragma unroll
    for (int c = 0; c < 4; ++c)
        #pragma unroll
        for (int q = 0; q < 4; ++q) {
            const int  p   = PI_[c][q];
            const bool pos = SG_[c][q] > 0;
            bf16x8 wr_s = pos ? wpos[p][0] : wneg[p][0];
            bf16x8 wi_s = pos ? wpos[p][1] : wneg[p][1];
            bf16x8 wi_m = pos ? wneg[p][1] : wpos[p][1];
            acc[c][0] = __builtin_amdgcn_mfma_f32_16x16x32_bf16(ax[q][0], wr_s, acc[c][0], 0, 0, 0);
            acc[c][0] = __builtin_amdgcn_mfma_f32_16x16x32_bf16(ax[q][1], wi_m, acc[c][0], 0, 0, 0);
            acc[c][1] = __builtin_amdgcn_mfma_f32_16x16x32_bf16(ax[q][1], wr_s, acc[c][1], 0, 0, 0);
            acc[c][1] = __builtin_amdgcn_mfma_f32_16x16x32_bf16(ax[q][0], wi_s, acc[c][1], 0, 0, 0);
        }

    // D layout: col(o) = lane&15, row(b) = (lane>>4)*4 + reg
    u32* __restrict__ dst = P + (size_t)bin * 4096;
    #pragma unroll
    for (int c = 0; c < 4; ++c)
        #pragma unroll
        for (int r = 0; r < 4; ++r) {
            int b_ = bh*16 + kg*4 + r;
            int o  = oh*16 + row;
            dst[c*1024 + b_*32 + o] = pk(make_float2(acc[c][0][r], acc[c][1][r]));
        }
}

// ---------------- transpose P: [bin][img] u32 -> PT[img][bin] u32 ----------------
__global__ __launch_bounds__(256) void pxpose_kernel(const u32* __restrict__ P,
                                                     u32* __restrict__ PT)
{
    const int bin0 = blockIdx.x * 32;
    const int img0 = blockIdx.y * 32;
    __shared__ u32 tile[32][33];
    const int tid = threadIdx.x;
    #pragma unroll
    for (int it = 0; it < 4; ++it) {
        int e = tid + it*256;
        int bi = e >> 5, im = e & 31;
        tile[bi][im] = P[(size_t)(bin0 + bi) * 4096 + img0 + im];
    }
    __syncthreads();
    #pragma unroll
    for (int it = 0; it < 4; ++it) {
        int e = tid + it*256;
        int im = e >> 5, bi = e & 31;
        PT[(size_t)(img0 + im) * NBIN + bin0 + bi] = tile[bi][im];
    }
}

// ---------------- inverse rfft2: one block per output image, 8x8 register FFT ----------------
__global__ __launch_bounds__(256) void fft_inv_kernel(const u32* __restrict__ PT,
                                                      float* __restrict__ out)
{
    const int bid = blockIdx.x;
    const int img = ((bid & 7) << 9) + (bid >> 3);   // chunked XCD swizzle
    const int c  = img >> 10;
    const int b  = (img >> 5) & 31;
    const int oc = img & 31;

    __shared__ u32    bufD[64*34];     // spectra packed [hf][k]
    __shared__ float2 bufA[33*LSTR];
    __shared__ float2 bufT[64*34];     // T[h][k]; reused as float out[4096]

    const int tid = threadIdx.x;
    const int g = tid >> 3, sub = tid & 7;
    float2 tw[8];
    #pragma unroll
    for (int j = 0; j < 8; ++j) {
        float sn, cs;
        __sincosf(PI2 * (float)(sub*j) / 64.f, &sn, &cs);
        tw[j] = make_float2(cs, sn);
    }

    const u32* __restrict__ srcP = PT + (size_t)img * NBIN;
    for (int t = tid; t < NBIN; t += 256) {
        int hf = t / 33, k = t - hf*33;
        bufD[hf*34 + k] = srcP[t];
    }
    __syncthreads();

    // IC1: column inverse dft8 over m2 + twiddle (33 k-problems)
    for (int p = g; p < 33; p += 32) {
        float2 v[8];
        #pragma unroll
        for (int m2 = 0; m2 < 8; ++m2) v[m2] = upk(bufD[(sub + 8*m2)*34 + p]);
        dft8<1>(v);
        #pragma unroll
        for (int j1 = 0; j1 < 8; ++j1)
            bufA[p*LSTR + sub*8 + j1] = cmul(v[j1], tw[j1]);
    }
    __syncthreads();

    // IC2: dft8 over n1 -> T[h = j1+8j2][k]
    for (int p = g; p < 33; p += 32) {
        float2 v[8];
        #pragma unroll
        for (int n1 = 0; n1 < 8; ++n1) v[n1] = bufA[p*LSTR + n1*8 + sub];
        dft8<1>(v);
        #pragma unroll
        for (int j2 = 0; j2 < 8; ++j2)
            bufT[(sub + 8*j2)*34 + p] = v[j2];
    }
    __syncthreads();

    // row prep (Hermitian-extend + pack row pairs) + inverse dft8 over n2 + twiddle
    {
        float2 v[8];
        const int h0 = 2*g, h1 = h0 + 1;
        #pragma unroll
        for (int n2 = 0; n2 < 8; ++n2) {
            int wp = sub + 8*n2;
            int m = (wp <= 32) ? wp : 64 - wp;
            float2 A = bufT[h0*34 + m];
            float2 B = bufT[h1*34 + m];
            if (m == 0 || m == 32) { A.y = 0.f; B.y = 0.f; }  // irfft ignores DC/Nyq imag
            float sg = (wp <= 32) ? 1.f : -1.f;
            A.y *= sg; B.y *= sg;
            v[n2] = make_float2(A.x - B.y, A.y + B.x);
        }
        dft8<1>(v);
        #pragma unroll
        for (int w1 = 0; w1 < 8; ++w1)
            bufA[g*LSTR + sub*8 + w1] = cmul(v[w1], tw[w1]);
    }
    __syncthreads();

    // row phase2: dft8 over n1 -> spatial w = w1+8w2; rows 2g (Re), 2g+1 (Im)
    float* obuf = (float*)bufT;
    {
        float2 v[8];
        #pragma unroll
        for (int n1 = 0; n1 < 8; ++n1) v[n1] = bufA[g*LSTR + n1*8 + sub];
        dft8<1>(v);
        const float sc = 1.f / 4096.f;
        const int h0 = 2*g, h1 = h0 + 1;
        #pragma unroll
        for (int w2 = 0; w2 < 8; ++w2) {
            int w = sub + 8*w2;
            obuf[h0*64 + ((w + 4*h0) & 63)] = v[w2].x * sc;
            obuf[h1*64 + ((w + 4*h1) & 63)] = v[w2].y * sc;
        }
    }
    __syncthreads();

    float* __restrict__ dst = out + ((size_t)b*128 + (size_t)c*32 + oc) * (FH*FW);
    for (int t = tid; t < 1024; t += 256) {
        int flat = t << 2, h = flat >> 6, w0 = flat & 63;
        float4 v = *(float4*)&obuf[h*64 + ((w0 + 4*h) & 63)];
        ((float4*)dst)[t] = v;
    }
}

extern "C" void kernel_launch(void* const* d_in, const int* in_sizes, int n_in,
                              void* d_out, int out_size, void* d_ws, size_t ws_size,
                              hipStream_t stream)
{
    const float* x   = (const float*)d_in[0];
    const float* krw = (const float*)d_in[1];
    const float* krx = (const float*)d_in[2];
    const float* kry = (const float*)d_in[3];
    const float* krz = (const float*)d_in[4];
    const float* kiw = (const float*)d_in[5];
    const float* kix = (const float*)d_in[6];
    const float* kiy = (const float*)d_in[7];
    const float* kiz = (const float*)d_in[8];

    // ws regions (34.6 MB each): [XT / PT] [WT] [Xs / P]
    const size_t R = (size_t)NBIN * 8192 * sizeof(u16);   // 34.6 MB
    u16* XT = (u16*)d_ws;
    u32* PT = (u32*)d_ws;                                  // alias: XT dead after contract
    u16* WT = (u16*)((char*)d_ws + R);
    u32* Xs = (u32*)((char*)d_ws + 2*R);
    u32* P  = Xs;                                          // alias: Xs dead after xpose
    float* out = (float*)d_out;

    prep_w_kernel<<<dim3(NBIN/16, 8), 256, 0, stream>>>(krw, krx, kry, krz,
                                                        kiw, kix, kiy, kiz, WT);
    fft_fwd_kernel<<<dim3(NIMG), 256, 0, stream>>>(x, Xs);
    xpose_x_kernel<<<dim3(128, NBIN/32), 256, 0, stream>>>(Xs, (u32*)XT);
    contract_kernel<<<dim3(NBIN), 256, 0, stream>>>(XT, WT, P);
    pxpose_kernel<<<dim3(NBIN/32, NIMG/32), 256, 0, stream>>>(P, PT);
    fft_inv_kernel<<<dim3(NIMG), 256, 0, stream>>>(PT, out);
}

// Round 6
// 156.542 us; speedup vs baseline: 1.3544x; 1.1449x over previous
//
#include <hip/hip_runtime.h>

#define FH 64
#define FW 64
#define NWF 33
#define NBIN (FH*NWF)      // 2112
#define NIMG 4096          // 4 * 32 * 32
#define PI2 6.283185307179586f
#define LSTR 67            // LDS float2 row stride

typedef unsigned short u16;
typedef unsigned int u32;
typedef __attribute__((ext_vector_type(8))) short bf16x8;
typedef __attribute__((ext_vector_type(4))) float f32x4;
typedef __attribute__((ext_vector_type(4))) int   i32x4;

__device__ __forceinline__ u16 f2bf(float f) {
    unsigned u = __float_as_uint(f);
    unsigned r = (u + 0x7FFFu + ((u >> 16) & 1u)) >> 16;   // RNE
    return (u16)r;
}
__device__ __forceinline__ float2 upk(u32 v) {
    return make_float2(__uint_as_float(v << 16), __uint_as_float(v & 0xFFFF0000u));
}
__device__ __forceinline__ u32 pk(float2 v) {
    return (u32)f2bf(v.x) | ((u32)f2bf(v.y) << 16);
}
__device__ __forceinline__ float2 cadd(float2 a, float2 b){ return make_float2(a.x+b.x, a.y+b.y); }
__device__ __forceinline__ float2 csub(float2 a, float2 b){ return make_float2(a.x-b.x, a.y-b.y); }
__device__ __forceinline__ float2 cmul(float2 a, float2 b){
    return make_float2(a.x*b.x - a.y*b.y, a.x*b.y + a.y*b.x);
}
template<int DIR> __device__ __forceinline__ float2 mulpmi(float2 a){
    return (DIR < 0) ? make_float2(a.y, -a.x) : make_float2(-a.y, a.x);
}

// 8-point DFT in registers, natural-order in/out. DIR=-1 fwd, +1 inv (unscaled).
template<int DIR> __device__ __forceinline__ void dft8(float2 v[8]) {
    const float s = 0.70710678118654752f;
    float2 u0=cadd(v[0],v[4]), u1=cadd(v[1],v[5]), u2=cadd(v[2],v[6]), u3=cadd(v[3],v[7]);
    float2 t0=csub(v[0],v[4]), t1=csub(v[1],v[5]), t2=csub(v[2],v[6]), t3=csub(v[3],v[7]);
    float2 w1, w3;
    if (DIR < 0) { w1 = make_float2(s*(t1.x+t1.y),  s*(t1.y-t1.x));
                   w3 = make_float2(s*(t3.y-t3.x), -s*(t3.x+t3.y)); }
    else         { w1 = make_float2(s*(t1.x-t1.y),  s*(t1.x+t1.y));
                   w3 = make_float2(-s*(t3.x+t3.y), s*(t3.x-t3.y)); }
    float2 w2 = mulpmi<DIR>(t2);
    float2 a0=cadd(u0,u2), a1=cadd(u1,u3), b0=csub(u0,u2), b1=mulpmi<DIR>(csub(u1,u3));
    float2 c0=cadd(t0,w2), c1=cadd(w1,w3), d0=csub(t0,w2), d1=mulpmi<DIR>(csub(w1,w3));
    v[0]=cadd(a0,a1); v[4]=csub(a0,a1);
    v[2]=cadd(b0,b1); v[6]=csub(b0,b1);
    v[1]=cadd(c0,c1); v[5]=csub(c0,c1);
    v[3]=cadd(d0,d1); v[7]=csub(d0,d1);
}

// ---------------- forward rfft2: one block per image, 8x8 register FFT ----------------
// Ping-pong LDS: phases alternate X->Y->X->...; 35.4 KB total -> 4 blocks/CU.
__global__ __launch_bounds__(256, 4) void fft_fwd_kernel(const float* __restrict__ x,
                                                         u32* __restrict__ Xs)
{
    const int img = blockIdx.x;        // q*1024 + b*32 + i
    const int q  = img >> 10;
    const int b  = (img >> 5) & 31;
    const int ci = img & 31;
    const float* __restrict__ src = x + ((size_t)b*128 + (size_t)q*32 + ci) * (FH*FW);

    __shared__ float2 bufX[33*LSTR];   // 17688 B
    __shared__ float2 bufY[33*LSTR];   // 17688 B

    const int tid = threadIdx.x;
    const int g = tid >> 3, sub = tid & 7;
    float2 tw[8];
    #pragma unroll
    for (int j = 0; j < 8; ++j) {
        float sn, cs;
        __sincosf(-PI2 * (float)(sub*j) / 64.f, &sn, &cs);
        tw[j] = make_float2(cs, sn);
    }

    // stage image into X with per-row rotation rot(h) = 8h + 4*(h>>3) (float4-aligned)
    float* simg = (float*)bufX;
    for (int t = tid; t < 1024; t += 256) {
        float4 v = ((const float4*)src)[t];
        int flat = t << 2, h = flat >> 6, w = flat & 63;
        int wr = (w + 8*h + 4*(h >> 3)) & 63;
        *(float4*)&simg[h*64 + wr] = v;
    }
    __syncthreads();

    // R1 (X->Y): packed row pair r=g, n1=sub: dft8 over n2 + twiddle
    {
        float2 v[8];
        const int h0 = 2*g, h1 = 2*g + 1;
        const int r0 = (8*h0 + 4*(h0 >> 3)) & 63, r1 = (8*h1 + 4*(h1 >> 3)) & 63;
        #pragma unroll
        for (int n2 = 0; n2 < 8; ++n2) {
            int w = sub + 8*n2;
            v[n2].x = simg[h0*64 + ((w + r0) & 63)];
            v[n2].y = simg[h1*64 + ((w + r1) & 63)];
        }
        dft8<-1>(v);
        #pragma unroll
        for (int k1 = 0; k1 < 8; ++k1)
            bufY[g*LSTR + sub*8 + k1] = cmul(v[k1], tw[k1]);
    }
    __syncthreads();

    // R2 (Y->X): dft8 over n1 -> Z[k1+8k2], natural store
    {
        float2 v[8];
        #pragma unroll
        for (int n1 = 0; n1 < 8; ++n1) v[n1] = bufY[g*LSTR + n1*8 + sub];
        dft8<-1>(v);
        #pragma unroll
        for (int k2 = 0; k2 < 8; ++k2) bufX[g*LSTR + sub + 8*k2] = v[k2];
    }
    __syncthreads();

    // unpack (X->Y): packed-row spectra -> column problems Y[p=k][h]
    for (int e = tid; e < 2112; e += 256) {
        int p = e >> 6, h = e & 63, r = h >> 1;
        float2 Zp = bufX[r*LSTR + p];
        float2 Zq = bufX[r*LSTR + ((64 - p) & 63)];
        float2 val;
        if ((h & 1) == 0) val = make_float2(0.5f*(Zp.x + Zq.x), 0.5f*(Zp.y - Zq.y));
        else              val = make_float2(0.5f*(Zp.y + Zq.y), 0.5f*(Zq.x - Zp.x));
        bufY[p*LSTR + h] = val;
    }
    __syncthreads();

    // C1 (Y->X): column dft8 over m2 + twiddle (33 problems over 32 groups)
    for (int p = g; p < 33; p += 32) {
        float2 v[8];
        #pragma unroll
        for (int m2 = 0; m2 < 8; ++m2) v[m2] = bufY[p*LSTR + sub + 8*m2];
        dft8<-1>(v);
        #pragma unroll
        for (int j1 = 0; j1 < 8; ++j1)
            bufX[p*LSTR + sub*8 + j1] = cmul(v[j1], tw[j1]);
    }
    __syncthreads();

    // C2 (X->sbin in Y): dft8 over n1 -> final spectra at hf = j1+8j2, pack bf16
    u32* sbin = (u32*)bufY;            // Y is dead after C1 reads
    for (int p = g; p < 33; p += 32) {
        float2 v[8];
        #pragma unroll
        for (int n1 = 0; n1 < 8; ++n1) v[n1] = bufX[p*LSTR + n1*8 + sub];
        dft8<-1>(v);
        #pragma unroll
        for (int j2 = 0; j2 < 8; ++j2)
            sbin[(sub + 8*j2)*34 + p] = pk(v[j2]);
    }
    __syncthreads();

    u32* __restrict__ dst = Xs + (size_t)img * NBIN;
    for (int t = tid; t < NBIN; t += 256) {
        int hf = t / 33, k = t - hf*33;
        dst[t] = sbin[hf*34 + k];
    }
}

// ---------------- transpose X: [img][bin] u32 -> [bin][q][ri][b][i] bf16 ----------------
__global__ __launch_bounds__(256) void xpose_x_kernel(const u32* __restrict__ Xs,
                                                      u32* __restrict__ XT)
{
    const int g    = blockIdx.x;        // q*32 + b
    const int bin0 = blockIdx.y * 32;
    __shared__ u32 tile[32][33];
    const int tid = threadIdx.x;
    #pragma unroll
    for (int it = 0; it < 4; ++it) {
        int e = tid + it*256;
        int imgL = e >> 5, binL = e & 31;
        tile[imgL][binL] = Xs[(size_t)(g*32 + imgL) * NBIN + bin0 + binL];
    }
    __syncthreads();
    const int q = g >> 5, b = g & 31;
    #pragma unroll
    for (int it = 0; it < 2; ++it) {
        int e = tid + it*256;          // 512 tasks: [binL][i-pair]
        int binL = e >> 4, pr = e & 15;
        u32 v0 = tile[pr*2][binL], v1 = tile[pr*2 + 1][binL];
        u32 re = (v0 & 0xFFFFu) | (v1 << 16);
        u32 im = (v0 >> 16) | (v1 & 0xFFFF0000u);
        size_t base = ((size_t)(bin0 + binL)*8 + q*2) * 512 + b*16 + pr;  // u32 units
        XT[base]       = re;
        XT[base + 512] = im;
    }
}

// ---------------- transpose W: [i][o][bin] f32 -> [bin][p][ri][o][i] bf16 ----------------
__global__ __launch_bounds__(256) void prep_w_kernel(
    const float* __restrict__ s0, const float* __restrict__ s1,
    const float* __restrict__ s2, const float* __restrict__ s3,
    const float* __restrict__ s4, const float* __restrict__ s5,
    const float* __restrict__ s6, const float* __restrict__ s7,
    u16* __restrict__ WT)
{
    const int a = blockIdx.y;           // ri*4 + p
    const int p = a & 3, ri = a >> 2;
    const float* __restrict__ src =
        (a==0)?s0:(a==1)?s1:(a==2)?s2:(a==3)?s3:(a==4)?s4:(a==5)?s5:(a==6)?s6:s7;
    const int bin0 = blockIdx.x * 16;
    __shared__ u16 lds[16][1032];
    const int tid = threadIdx.x;
    for (int it = 0; it < 64; ++it) {
        int e = tid + it*256;
        int io = e >> 4, binL = e & 15;
        float v = src[(size_t)io * NBIN + bin0 + binL];
        int i = io >> 5, o = io & 31;
        lds[binL][o*32 + i] = f2bf(v);
    }
    __syncthreads();
    #pragma unroll
    for (int it = 0; it < 8; ++it) {
        int c = tid + it*256;
        int binL = c >> 7, ch = c & 127;
        bf16x8 v = *(const bf16x8*)&lds[binL][ch*8];
        size_t dst = ((size_t)((bin0 + binL)*4 + p)*2 + ri)*1024 + ch*8;
        *(bf16x8*)(WT + dst) = v;
    }
}

// ---------------- per-bin quaternion contraction via MFMA ----------------
__global__ __launch_bounds__(256) void contract_kernel(
    const u16* __restrict__ XT, const u16* __restrict__ WT,
    u32* __restrict__ P)
{
    const int bid  = blockIdx.x;
    const int bin  = (bid & 7) * (NBIN/8) + (bid >> 3);   // chunked XCD swizzle
    const int wid  = threadIdx.x >> 6;
    const int lane = threadIdx.x & 63;
    const int bh = wid >> 1, oh = wid & 1;
    const int row = lane & 15, kg = lane >> 4;

    const u16* __restrict__ xb = XT + (size_t)bin * 8192;
    const u16* __restrict__ wb = WT + (size_t)bin * 8192;

    bf16x8 ax[4][2];
    #pragma unroll
    for (int q = 0; q < 4; ++q)
        #pragma unroll
        for (int ri = 0; ri < 2; ++ri)
            ax[q][ri] = *(const bf16x8*)(xb + ((q*2 + ri)*32 + bh*16 + row)*32 + kg*8);

    bf16x8 wpos[4][2], wneg[4][2];
    #pragma unroll
    for (int p = 0; p < 4; ++p)
        #pragma unroll
        for (int ri = 0; ri < 2; ++ri) {
            bf16x8 w = *(const bf16x8*)(wb + ((p*2 + ri)*32 + oh*16 + row)*32 + kg*8);
            wpos[p][ri] = w;
            i32x4 t = __builtin_bit_cast(i32x4, w);
            t ^= (int)0x80008000;
            wneg[p][ri] = __builtin_bit_cast(bf16x8, t);
        }

    f32x4 acc[4][2];
    #pragma unroll
    for (int c = 0; c < 4; ++c)
        #pragma unroll
        for (int ri = 0; ri < 2; ++ri)
            acc[c][ri] = (f32x4){0.f, 0.f, 0.f, 0.f};

    constexpr int PI_[4][4] = {{0,1,2,3},{1,0,3,2},{2,3,0,1},{3,2,1,0}};
    constexpr int SG_[4][4] = {{1,-1,-1,-1},{1,1,-1,1},{1,1,1,-1},{1,-1,1,1}};
    #pragma unroll
    for (int c = 0; c < 4; ++c)
        #pragma unroll
        for (int q = 0; q < 4; ++q) {
            const int  p   = PI_[c][q];
            const bool pos = SG_[c][q] > 0;
            bf16x8 wr_s = pos ? wpos[p][0] : wneg[p][0];
            bf16x8 wi_s = pos ? wpos[p][1] : wneg[p][1];
            bf16x8 wi_m = pos ? wneg[p][1] : wpos[p][1];
            acc[c][0] = __builtin_amdgcn_mfma_f32_16x16x32_bf16(ax[q][0], wr_s, acc[c][0], 0, 0, 0);
            acc[c][0] = __builtin_amdgcn_mfma_f32_16x16x32_bf16(ax[q][1], wi_m, acc[c][0], 0, 0, 0);
            acc[c][1] = __builtin_amdgcn_mfma_f32_16x16x32_bf16(ax[q][1], wr_s, acc[c][1], 0, 0, 0);
            acc[c][1] = __builtin_amdgcn_mfma_f32_16x16x32_bf16(ax[q][0], wi_s, acc[c][1], 0, 0, 0);
        }

    u32* __restrict__ dst = P + (size_t)bin * 4096;
    #pragma unroll
    for (int c = 0; c < 4; ++c)
        #pragma unroll
        for (int r = 0; r < 4; ++r) {
            int b_ = bh*16 + kg*4 + r;
            int o  = oh*16 + row;
            dst[c*1024 + b_*32 + o] = pk(make_float2(acc[c][0][r], acc[c][1][r]));
        }
}

// ---------------- transpose P: [bin][img] u32 -> PT[img][bin] u32 ----------------
__global__ __launch_bounds__(256) void pxpose_kernel(const u32* __restrict__ P,
                                                     u32* __restrict__ PT)
{
    const int bin0 = blockIdx.x * 32;
    const int img0 = blockIdx.y * 32;
    __shared__ u32 tile[32][33];
    const int tid = threadIdx.x;
    #pragma unroll
    for (int it = 0; it < 4; ++it) {
        int e = tid + it*256;
        int bi = e >> 5, im = e & 31;
        tile[bi][im] = P[(size_t)(bin0 + bi) * 4096 + img0 + im];
    }
    __syncthreads();
    #pragma unroll
    for (int it = 0; it < 4; ++it) {
        int e = tid + it*256;
        int im = e >> 5, bi = e & 31;
        PT[(size_t)(img0 + im) * NBIN + bin0 + bi] = tile[bi][im];
    }
}

// ---------------- inverse rfft2: one block per output image, 8x8 register FFT ----------------
__global__ __launch_bounds__(256, 4) void fft_inv_kernel(const u32* __restrict__ PT,
                                                         float* __restrict__ out)
{
    const int bid = blockIdx.x;
    const int img = ((bid & 7) << 9) + (bid >> 3);   // chunked XCD swizzle
    const int c  = img >> 10;
    const int b  = (img >> 5) & 31;
    const int oc = img & 31;

    __shared__ float2 bufX[33*LSTR];   // 17688 B
    __shared__ float2 bufY[33*LSTR];   // 17688 B

    const int tid = threadIdx.x;
    const int g = tid >> 3, sub = tid & 7;
    float2 tw[8];
    #pragma unroll
    for (int j = 0; j < 8; ++j) {
        float sn, cs;
        __sincosf(PI2 * (float)(sub*j) / 64.f, &sn, &cs);
        tw[j] = make_float2(cs, sn);
    }

    // load packed spectra into X: bufD[hf*34 + k]
    u32* bufD = (u32*)bufX;
    const u32* __restrict__ srcP = PT + (size_t)img * NBIN;
    for (int t = tid; t < NBIN; t += 256) {
        int hf = t / 33, k = t - hf*33;
        bufD[hf*34 + k] = srcP[t];
    }
    __syncthreads();

    // IC1 (X->Y): column inverse dft8 over m2 + twiddle (33 k-problems)
    for (int p = g; p < 33; p += 32) {
        float2 v[8];
        #pragma unroll
        for (int m2 = 0; m2 < 8; ++m2) v[m2] = upk(bufD[(sub + 8*m2)*34 + p]);
        dft8<1>(v);
        #pragma unroll
        for (int j1 = 0; j1 < 8; ++j1)
            bufY[p*LSTR + sub*8 + j1] = cmul(v[j1], tw[j1]);
    }
    __syncthreads();

    // IC2 (Y->X): dft8 over n1 -> T[h = j1+8j2][k] in bufT
    float2* bufT = bufX;               // [64*34] = 17408 B fits
    for (int p = g; p < 33; p += 32) {
        float2 v[8];
        #pragma unroll
        for (int n1 = 0; n1 < 8; ++n1) v[n1] = bufY[p*LSTR + n1*8 + sub];
        dft8<1>(v);
        #pragma unroll
        for (int j2 = 0; j2 < 8; ++j2)
            bufT[(sub + 8*j2)*34 + p] = v[j2];
    }
    __syncthreads();

    // row prep (X->Y): Hermitian-extend + pack row pairs + inverse dft8 over n2 + twiddle
    {
        float2 v[8];
        const int h0 = 2*g, h1 = h0 + 1;
        #pragma unroll
        for (int n2 = 0; n2 < 8; ++n2) {
            int wp = sub + 8*n2;
            int m = (wp <= 32) ? wp : 64 - wp;
            float2 A = bufT[h0*34 + m];
            float2 B = bufT[h1*34 + m];
            if (m == 0 || m == 32) { A.y = 0.f; B.y = 0.f; }  // irfft ignores DC/Nyq imag
            float sg = (wp <= 32) ? 1.f : -1.f;
            A.y *= sg; B.y *= sg;
            v[n2] = make_float2(A.x - B.y, A.y + B.x);
        }
        dft8<1>(v);
        #pragma unroll
        for (int w1 = 0; w1 < 8; ++w1)
            bufY[g*LSTR + sub*8 + w1] = cmul(v[w1], tw[w1]);
    }
    __syncthreads();

    // row phase2 (Y->X): dft8 over n1 -> spatial w = w1+8w2; rows 2g (Re), 2g+1 (Im)
    float* obuf = (float*)bufX;        // 16384 B fits
    {
        float2 v[8];
        #pragma unroll
        for (int n1 = 0; n1 < 8; ++n1) v[n1] = bufY[g*LSTR + n1*8 + sub];
        dft8<1>(v);
        const float sc = 1.f / 4096.f;
        const int h0 = 2*g, h1 = h0 + 1;
        #pragma unroll
        for (int w2 = 0; w2 < 8; ++w2) {
            int w = sub + 8*w2;
            obuf[h0*64 + ((w + 4*h0) & 63)] = v[w2].x * sc;
            obuf[h1*64 + ((w + 4*h1) & 63)] = v[w2].y * sc;
        }
    }
    __syncthreads();

    float* __restrict__ dst = out + ((size_t)b*128 + (size_t)c*32 + oc) * (FH*FW);
    for (int t = tid; t < 1024; t += 256) {
        int flat = t << 2, h = flat >> 6, w0 = flat & 63;
        float4 v = *(float4*)&obuf[h*64 + ((w0 + 4*h) & 63)];
        ((float4*)dst)[t] = v;
    }
}

extern "C" void kernel_launch(void* const* d_in, const int* in_sizes, int n_in,
                              void* d_out, int out_size, void* d_ws, size_t ws_size,
                              hipStream_t stream)
{
    const float* x   = (const float*)d_in[0];
    const float* krw = (const float*)d_in[1];
    const float* krx = (const float*)d_in[2];
    const float* kry = (const float*)d_in[3];
    const float* krz = (const float*)d_in[4];
    const float* kiw = (const float*)d_in[5];
    const float* kix = (const float*)d_in[6];
    const float* kiy = (const float*)d_in[7];
    const float* kiz = (const float*)d_in[8];

    // ws regions (34.6 MB each): [XT / PT] [WT] [Xs / P]
    const size_t R = (size_t)NBIN * 8192 * sizeof(u16);   // 34.6 MB
    u16* XT = (u16*)d_ws;
    u32* PT = (u32*)d_ws;                                  // alias: XT dead after contract
    u16* WT = (u16*)((char*)d_ws + R);
    u32* Xs = (u32*)((char*)d_ws + 2*R);
    u32* P  = Xs;                                          // alias: Xs dead after xpose
    float* out = (float*)d_out;

    prep_w_kernel<<<dim3(NBIN/16, 8), 256, 0, stream>>>(krw, krx, kry, krz,
                                                        kiw, kix, kiy, kiz, WT);
    fft_fwd_kernel<<<dim3(NIMG), 256, 0, stream>>>(x, Xs);
    xpose_x_kernel<<<dim3(128, NBIN/32), 256, 0, stream>>>(Xs, (u32*)XT);
    contract_kernel<<<dim3(NBIN), 256, 0, stream>>>(XT, WT, P);
    pxpose_kernel<<<dim3(NBIN/32, NIMG/32), 256, 0, stream>>>(P, PT);
    fft_inv_kernel<<<dim3(NIMG), 256, 0, stream>>>(PT, out);
}

// Round 7
// 148.721 us; speedup vs baseline: 1.4256x; 1.0526x over previous
//
#include <hip/hip_runtime.h>

#define FH 64
#define FW 64
#define NWF 33
#define NBIN (FH*NWF)      // 2112
#define NIMG 4096          // 4 * 32 * 32
#define PI2 6.283185307179586f
#define LSTR 67            // LDS float2 row stride (inv kernel)

typedef unsigned short u16;
typedef unsigned int u32;
typedef __attribute__((ext_vector_type(8))) short bf16x8;
typedef __attribute__((ext_vector_type(8))) _Float16 f16x8;
typedef __attribute__((ext_vector_type(4))) unsigned short u16x4;
typedef __attribute__((ext_vector_type(4))) float f32x4;
typedef __attribute__((ext_vector_type(4))) int   i32x4;

__device__ __forceinline__ u16 f2bf(float f) {
    unsigned u = __float_as_uint(f);
    unsigned r = (u + 0x7FFFu + ((u >> 16) & 1u)) >> 16;   // RNE
    return (u16)r;
}
__device__ __forceinline__ u16 f2h(float f) {
    _Float16 h = (_Float16)f;
    return __builtin_bit_cast(u16, h);
}
__device__ __forceinline__ float2 upk(u32 v) {
    return make_float2(__uint_as_float(v << 16), __uint_as_float(v & 0xFFFF0000u));
}
__device__ __forceinline__ u32 pk(float2 v) {
    return (u32)f2bf(v.x) | ((u32)f2bf(v.y) << 16);
}
__device__ __forceinline__ f16x8 negh(f16x8 v) {
    i32x4 t = __builtin_bit_cast(i32x4, v);
    t ^= (int)0x80008000;
    return __builtin_bit_cast(f16x8, t);
}
__device__ __forceinline__ float2 cadd(float2 a, float2 b){ return make_float2(a.x+b.x, a.y+b.y); }
__device__ __forceinline__ float2 csub(float2 a, float2 b){ return make_float2(a.x-b.x, a.y-b.y); }
__device__ __forceinline__ float2 cmul(float2 a, float2 b){
    return make_float2(a.x*b.x - a.y*b.y, a.x*b.y + a.y*b.x);
}
template<int DIR> __device__ __forceinline__ float2 mulpmi(float2 a){
    return (DIR < 0) ? make_float2(a.y, -a.x) : make_float2(-a.y, a.x);
}

// 8-point DFT in registers (inv kernel), natural-order in/out.
template<int DIR> __device__ __forceinline__ void dft8(float2 v[8]) {
    const float s = 0.70710678118654752f;
    float2 u0=cadd(v[0],v[4]), u1=cadd(v[1],v[5]), u2=cadd(v[2],v[6]), u3=cadd(v[3],v[7]);
    float2 t0=csub(v[0],v[4]), t1=csub(v[1],v[5]), t2=csub(v[2],v[6]), t3=csub(v[3],v[7]);
    float2 w1, w3;
    if (DIR < 0) { w1 = make_float2(s*(t1.x+t1.y),  s*(t1.y-t1.x));
                   w3 = make_float2(s*(t3.y-t3.x), -s*(t3.x+t3.y)); }
    else         { w1 = make_float2(s*(t1.x-t1.y),  s*(t1.x+t1.y));
                   w3 = make_float2(-s*(t3.x+t3.y), s*(t3.x-t3.y)); }
    float2 w2 = mulpmi<DIR>(t2);
    float2 a0=cadd(u0,u2), a1=cadd(u1,u3), b0=csub(u0,u2), b1=mulpmi<DIR>(csub(u1,u3));
    float2 c0=cadd(t0,w2), c1=cadd(w1,w3), d0=csub(t0,w2), d1=mulpmi<DIR>(csub(w1,w3));
    v[0]=cadd(a0,a1); v[4]=csub(a0,a1);
    v[2]=cadd(b0,b1); v[6]=csub(b0,b1);
    v[1]=cadd(c0,c1); v[5]=csub(c0,c1);
    v[3]=cadd(d0,d1); v[7]=csub(d0,d1);
}

// ---------------- forward rfft2 via MFMA-DFT: one wave per image ----------------
// S = x * C64 (row pass), X = (C64 - i*S64) * S (col pass); C64/S64 symmetric f16.
__global__ __launch_bounds__(256, 2) void fft_fwd_kernel(const float* __restrict__ x,
                                                         u32* __restrict__ Xs)
{
    __shared__ __align__(16) u16 mats[2][64*72];   // [cos/sin][a*72+b], symmetric
    __shared__ __align__(16) u16 wbuf[4][6912];    // per-wave: xb / S_T / sbin

    const int tid  = threadIdx.x;
    const int lane = tid & 63;
    const int wid  = tid >> 6;
    const int a16  = lane & 15;
    const int q    = lane >> 4;

    const int img = blockIdx.x * 4 + wid;          // qc*1024 + b*32 + ci
    const int qc = img >> 10;
    const int b  = (img >> 5) & 31;
    const int ci = img & 31;
    const float* __restrict__ src = x + ((size_t)b*128 + (size_t)qc*32 + ci) * (FH*FW);

    // init DFT matrices: C64[a][b]=cos(2pi ab/64), S64=sin
    for (int t = tid; t < 4096; t += 256) {
        int a = t >> 6, bb = t & 63;
        float sn, cs;
        __sincosf(PI2 * (float)((a*bb) & 63) * (1.f/64.f), &sn, &cs);
        mats[0][a*72 + bb] = f2h(cs);
        mats[1][a*72 + bb] = f2h(sn);
    }
    // stage x -> xb f16 [h][w], stride 64
    u16* xb = wbuf[wid];
    for (int i = 0; i < 16; ++i) {
        int idx4 = i*64 + lane;
        float4 v = ((const float4*)src)[idx4];
        int h = idx4 >> 4, c4 = (idx4 & 15) * 4;
        u16x4 hv = { f2h(v.x), f2h(v.y), f2h(v.z), f2h(v.w) };
        *(u16x4*)&xb[h*64 + c4] = hv;
    }
    __syncthreads();

    // preload all x A-fragments: [mt][ks], m=h=16mt+a16, k=w=32ks+8q..+7
    f16x8 xf[4][2];
    #pragma unroll
    for (int mt = 0; mt < 4; ++mt)
        #pragma unroll
        for (int ks = 0; ks < 2; ++ks)
            xf[mt][ks] = *(const f16x8*)&xb[(16*mt + a16)*64 + ks*32 + q*8];
    __syncthreads();

    // step1: S_re = x*C64, S_im = -x*S64; store transposed S_T[ri][k][h], stride 72
    u16* ST = wbuf[wid];
    #pragma unroll
    for (int mt = 0; mt < 4; ++mt) {
        f32x4 are[3], aim[3];
        #pragma unroll
        for (int nt = 0; nt < 3; ++nt) { are[nt] = (f32x4){0,0,0,0}; aim[nt] = (f32x4){0,0,0,0}; }
        #pragma unroll
        for (int nt = 0; nt < 3; ++nt)
            #pragma unroll
            for (int ks = 0; ks < 2; ++ks) {
                const int rb = (16*nt + a16)*72 + ks*32 + q*8;
                f16x8 cf = *(const f16x8*)&mats[0][rb];
                f16x8 sf = *(const f16x8*)&mats[1][rb];
                are[nt] = __builtin_amdgcn_mfma_f32_16x16x32_f16(xf[mt][ks], cf, are[nt], 0, 0, 0);
                aim[nt] = __builtin_amdgcn_mfma_f32_16x16x32_f16(xf[mt][ks], negh(sf), aim[nt], 0, 0, 0);
            }
        const int hb = 16*mt + 4*q;
        #pragma unroll
        for (int nt = 0; nt < 3; ++nt) {
            u16x4 re4 = { f2h(are[nt][0]), f2h(are[nt][1]), f2h(are[nt][2]), f2h(are[nt][3]) };
            u16x4 im4 = { f2h(aim[nt][0]), f2h(aim[nt][1]), f2h(aim[nt][2]), f2h(aim[nt][3]) };
            *(u16x4*)&ST[(16*nt + a16)*72 + hb]        = re4;
            *(u16x4*)&ST[(48 + 16*nt + a16)*72 + hb]   = im4;
        }
    }
    __syncthreads();

    // step2: preload S B-fragments [ri][nt][ks] (ST dead afterwards)
    f16x8 bfr[2][3][2];
    #pragma unroll
    for (int ri = 0; ri < 2; ++ri)
        #pragma unroll
        for (int nt = 0; nt < 3; ++nt)
            #pragma unroll
            for (int ks = 0; ks < 2; ++ks)
                bfr[ri][nt][ks] = *(const f16x8*)&ST[(ri*48 + 16*nt + a16)*72 + ks*32 + q*8];
    __syncthreads();

    // X_re = C*S_re + S*S_im ; X_im = C*S_im - S*S_re; pack bf16 into sbin
    u32* sbin = (u32*)wbuf[wid];
    #pragma unroll
    for (int mt = 0; mt < 4; ++mt) {
        f16x8 cfa[2], sfa[2], nsf[2];
        #pragma unroll
        for (int ks = 0; ks < 2; ++ks) {
            const int rb = (16*mt + a16)*72 + ks*32 + q*8;
            cfa[ks] = *(const f16x8*)&mats[0][rb];
            sfa[ks] = *(const f16x8*)&mats[1][rb];
            nsf[ks] = negh(sfa[ks]);
        }
        #pragma unroll
        for (int nt = 0; nt < 3; ++nt) {
            f32x4 xre = (f32x4){0,0,0,0}, xim = (f32x4){0,0,0,0};
            #pragma unroll
            for (int ks = 0; ks < 2; ++ks) {
                xre = __builtin_amdgcn_mfma_f32_16x16x32_f16(cfa[ks], bfr[0][nt][ks], xre, 0, 0, 0);
                xre = __builtin_amdgcn_mfma_f32_16x16x32_f16(sfa[ks], bfr[1][nt][ks], xre, 0, 0, 0);
                xim = __builtin_amdgcn_mfma_f32_16x16x32_f16(cfa[ks], bfr[1][nt][ks], xim, 0, 0, 0);
                xim = __builtin_amdgcn_mfma_f32_16x16x32_f16(nsf[ks], bfr[0][nt][ks], xim, 0, 0, 0);
            }
            const int k = 16*nt + a16;
            if (k < 33) {
                #pragma unroll
                for (int r = 0; r < 4; ++r)
                    sbin[(16*mt + 4*q + r)*34 + k] = pk(make_float2(xre[r], xim[r]));
            }
        }
    }
    __syncthreads();

    u32* __restrict__ dst = Xs + (size_t)img * NBIN;
    for (int i = 0; i < 33; ++i) {
        int t = i*64 + lane;               // 33*64 = 2112 exactly
        int hf = t / 33;
        dst[t] = sbin[hf*34 + (t - hf*33)];
    }
}

// ---------------- transpose X: [img][bin] u32 -> [bin][q][ri][b][i] bf16 ----------------
__global__ __launch_bounds__(256) void xpose_x_kernel(const u32* __restrict__ Xs,
                                                      u32* __restrict__ XT)
{
    const int g    = blockIdx.x;        // q*32 + b
    const int bin0 = blockIdx.y * 32;
    __shared__ u32 tile[32][33];
    const int tid = threadIdx.x;
    #pragma unroll
    for (int it = 0; it < 4; ++it) {
        int e = tid + it*256;
        int imgL = e >> 5, binL = e & 31;
        tile[imgL][binL] = Xs[(size_t)(g*32 + imgL) * NBIN + bin0 + binL];
    }
    __syncthreads();
    const int q = g >> 5, b = g & 31;
    #pragma unroll
    for (int it = 0; it < 2; ++it) {
        int e = tid + it*256;          // 512 tasks: [binL][i-pair]
        int binL = e >> 4, pr = e & 15;
        u32 v0 = tile[pr*2][binL], v1 = tile[pr*2 + 1][binL];
        u32 re = (v0 & 0xFFFFu) | (v1 << 16);
        u32 im = (v0 >> 16) | (v1 & 0xFFFF0000u);
        size_t base = ((size_t)(bin0 + binL)*8 + q*2) * 512 + b*16 + pr;  // u32 units
        XT[base]       = re;
        XT[base + 512] = im;
    }
}

// ---------------- transpose W: [i][o][bin] f32 -> [bin][p][ri][o][i] bf16 ----------------
__global__ __launch_bounds__(256) void prep_w_kernel(
    const float* __restrict__ s0, const float* __restrict__ s1,
    const float* __restrict__ s2, const float* __restrict__ s3,
    const float* __restrict__ s4, const float* __restrict__ s5,
    const float* __restrict__ s6, const float* __restrict__ s7,
    u16* __restrict__ WT)
{
    const int a = blockIdx.y;           // ri*4 + p
    const int p = a & 3, ri = a >> 2;
    const float* __restrict__ src =
        (a==0)?s0:(a==1)?s1:(a==2)?s2:(a==3)?s3:(a==4)?s4:(a==5)?s5:(a==6)?s6:s7;
    const int bin0 = blockIdx.x * 16;
    __shared__ u16 lds[16][1032];
    const int tid = threadIdx.x;
    for (int it = 0; it < 64; ++it) {
        int e = tid + it*256;
        int io = e >> 4, binL = e & 15;
        float v = src[(size_t)io * NBIN + bin0 + binL];
        int i = io >> 5, o = io & 31;
        lds[binL][o*32 + i] = f2bf(v);
    }
    __syncthreads();
    #pragma unroll
    for (int it = 0; it < 8; ++it) {
        int c = tid + it*256;
        int binL = c >> 7, ch = c & 127;
        bf16x8 v = *(const bf16x8*)&lds[binL][ch*8];
        size_t dst = ((size_t)((bin0 + binL)*4 + p)*2 + ri)*1024 + ch*8;
        *(bf16x8*)(WT + dst) = v;
    }
}

// ---------------- per-bin quaternion contraction via MFMA ----------------
__global__ __launch_bounds__(256) void contract_kernel(
    const u16* __restrict__ XT, const u16* __restrict__ WT,
    u32* __restrict__ P)
{
    const int bid  = blockIdx.x;
    const int bin  = (bid & 7) * (NBIN/8) + (bid >> 3);   // chunked XCD swizzle
    const int wid  = threadIdx.x >> 6;
    const int lane = threadIdx.x & 63;
    const int bh = wid >> 1, oh = wid & 1;
    const int row = lane & 15, kg = lane >> 4;

    const u16* __restrict__ xb = XT + (size_t)bin * 8192;
    const u16* __restrict__ wb = WT + (size_t)bin * 8192;

    bf16x8 ax[4][2];
    #pragma unroll
    for (int q = 0; q < 4; ++q)
        #pragma unroll
        for (int ri = 0; ri < 2; ++ri)
            ax[q][ri] = *(const bf16x8*)(xb + ((q*2 + ri)*32 + bh*16 + row)*32 + kg*8);

    bf16x8 wpos[4][2], wneg[4][2];
    #pragma unroll
    for (int p = 0; p < 4; ++p)
        #pragma unroll
        for (int ri = 0; ri < 2; ++ri) {
            bf16x8 w = *(const bf16x8*)(wb + ((p*2 + ri)*32 + oh*16 + row)*32 + kg*8);
            wpos[p][ri] = w;
            i32x4 t = __builtin_bit_cast(i32x4, w);
            t ^= (int)0x80008000;
            wneg[p][ri] = __builtin_bit_cast(bf16x8, t);
        }

    f32x4 acc[4][2];
    #pragma unroll
    for (int c = 0; c < 4; ++c)
        #pragma unroll
        for (int ri = 0; ri < 2; ++ri)
            acc[c][ri] = (f32x4){0.f, 0.f, 0.f, 0.f};

    constexpr int PI_[4][4] = {{0,1,2,3},{1,0,3,2},{2,3,0,1},{3,2,1,0}};
    constexpr int SG_[4][4] = {{1,-1,-1,-1},{1,1,-1,1},{1,1,1,-1},{1,-1,1,1}};
    #pragma unroll
    for (int c = 0; c < 4; ++c)
        #pragma unroll
        for (int q = 0; q < 4; ++q) {
            const int  p   = PI_[c][q];
            const bool pos = SG_[c][q] > 0;
            bf16x8 wr_s = pos ? wpos[p][0] : wneg[p][0];
            bf16x8 wi_s = pos ? wpos[p][1] : wneg[p][1];
            bf16x8 wi_m = pos ? wneg[p][1] : wpos[p][1];
            acc[c][0] = __builtin_amdgcn_mfma_f32_16x16x32_bf16(ax[q][0], wr_s, acc[c][0], 0, 0, 0);
            acc[c][0] = __builtin_amdgcn_mfma_f32_16x16x32_bf16(ax[q][1], wi_m, acc[c][0], 0, 0, 0);
            acc[c][1] = __builtin_amdgcn_mfma_f32_16x16x32_bf16(ax[q][1], wr_s, acc[c][1], 0, 0, 0);
            acc[c][1] = __builtin_amdgcn_mfma_f32_16x16x32_bf16(ax[q][0], wi_s, acc[c][1], 0, 0, 0);
        }

    u32* __restrict__ dst = P + (size_t)bin * 4096;
    #pragma unroll
    for (int c = 0; c < 4; ++c)
        #pragma unroll
        for (int r = 0; r < 4; ++r) {
            int b_ = bh*16 + kg*4 + r;
            int o  = oh*16 + row;
            dst[c*1024 + b_*32 + o] = pk(make_float2(acc[c][0][r], acc[c][1][r]));
        }
}

// ---------------- transpose P: [bin][img] u32 -> PT[img][bin] u32 ----------------
__global__ __launch_bounds__(256) void pxpose_kernel(const u32* __restrict__ P,
                                                     u32* __restrict__ PT)
{
    const int bin0 = blockIdx.x * 32;
    const int img0 = blockIdx.y * 32;
    __shared__ u32 tile[32][33];
    const int tid = threadIdx.x;
    #pragma unroll
    for (int it = 0; it < 4; ++it) {
        int e = tid + it*256;
        int bi = e >> 5, im = e & 31;
        tile[bi][im] = P[(size_t)(bin0 + bi) * 4096 + img0 + im];
    }
    __syncthreads();
    #pragma unroll
    for (int it = 0; it < 4; ++it) {
        int e = tid + it*256;
        int im = e >> 5, bi = e & 31;
        PT[(size_t)(img0 + im) * NBIN + bin0 + bi] = tile[bi][im];
    }
}

// ---------------- inverse rfft2: one block per output image, 8x8 register FFT ----------------
__global__ __launch_bounds__(256, 4) void fft_inv_kernel(const u32* __restrict__ PT,
                                                         float* __restrict__ out)
{
    const int bid = blockIdx.x;
    const int img = ((bid & 7) << 9) + (bid >> 3);   // chunked XCD swizzle
    const int c  = img >> 10;
    const int b  = (img >> 5) & 31;
    const int oc = img & 31;

    __shared__ float2 bufX[33*LSTR];   // 17688 B
    __shared__ float2 bufY[33*LSTR];   // 17688 B

    const int tid = threadIdx.x;
    const int g = tid >> 3, sub = tid & 7;
    float2 tw[8];
    #pragma unroll
    for (int j = 0; j < 8; ++j) {
        float sn, cs;
        __sincosf(PI2 * (float)(sub*j) / 64.f, &sn, &cs);
        tw[j] = make_float2(cs, sn);
    }

    // load packed spectra into X: bufD[hf*34 + k]
    u32* bufD = (u32*)bufX;
    const u32* __restrict__ srcP = PT + (size_t)img * NBIN;
    for (int t = tid; t < NBIN; t += 256) {
        int hf = t / 33, k = t - hf*33;
        bufD[hf*34 + k] = srcP[t];
    }
    __syncthreads();

    // IC1 (X->Y): column inverse dft8 over m2 + twiddle (33 k-problems)
    for (int p = g; p < 33; p += 32) {
        float2 v[8];
        #pragma unroll
        for (int m2 = 0; m2 < 8; ++m2) v[m2] = upk(bufD[(sub + 8*m2)*34 + p]);
        dft8<1>(v);
        #pragma unroll
        for (int j1 = 0; j1 < 8; ++j1)
            bufY[p*LSTR + sub*8 + j1] = cmul(v[j1], tw[j1]);
    }
    __syncthreads();

    // IC2 (Y->X): dft8 over n1 -> T[h = j1+8j2][k] in bufT
    float2* bufT = bufX;               // [64*34] fits
    for (int p = g; p < 33; p += 32) {
        float2 v[8];
        #pragma unroll
        for (int n1 = 0; n1 < 8; ++n1) v[n1] = bufY[p*LSTR + n1*8 + sub];
        dft8<1>(v);
        #pragma unroll
        for (int j2 = 0; j2 < 8; ++j2)
            bufT[(sub + 8*j2)*34 + p] = v[j2];
    }
    __syncthreads();

    // row prep (X->Y): Hermitian-extend + pack row pairs + inverse dft8 over n2 + twiddle
    {
        float2 v[8];
        const int h0 = 2*g, h1 = h0 + 1;
        #pragma unroll
        for (int n2 = 0; n2 < 8; ++n2) {
            int wp = sub + 8*n2;
            int m = (wp <= 32) ? wp : 64 - wp;
            float2 A = bufT[h0*34 + m];
            float2 B = bufT[h1*34 + m];
            if (m == 0 || m == 32) { A.y = 0.f; B.y = 0.f; }  // irfft ignores DC/Nyq imag
            float sg = (wp <= 32) ? 1.f : -1.f;
            A.y *= sg; B.y *= sg;
            v[n2] = make_float2(A.x - B.y, A.y + B.x);
        }
        dft8<1>(v);
        #pragma unroll
        for (int w1 = 0; w1 < 8; ++w1)
            bufY[g*LSTR + sub*8 + w1] = cmul(v[w1], tw[w1]);
    }
    __syncthreads();

    // row phase2 (Y->X): dft8 over n1 -> spatial w = w1+8w2; rows 2g (Re), 2g+1 (Im)
    float* obuf = (float*)bufX;
    {
        float2 v[8];
        #pragma unroll
        for (int n1 = 0; n1 < 8; ++n1) v[n1] = bufY[g*LSTR + n1*8 + sub];
        dft8<1>(v);
        const float sc = 1.f / 4096.f;
        const int h0 = 2*g, h1 = h0 + 1;
        #pragma unroll
        for (int w2 = 0; w2 < 8; ++w2) {
            int w = sub + 8*w2;
            obuf[h0*64 + ((w + 4*h0) & 63)] = v[w2].x * sc;
            obuf[h1*64 + ((w + 4*h1) & 63)] = v[w2].y * sc;
        }
    }
    __syncthreads();

    float* __restrict__ dst = out + ((size_t)b*128 + (size_t)c*32 + oc) * (FH*FW);
    for (int t = tid; t < 1024; t += 256) {
        int flat = t << 2, h = flat >> 6, w0 = flat & 63;
        float4 v = *(float4*)&obuf[h*64 + ((w0 + 4*h) & 63)];
        ((float4*)dst)[t] = v;
    }
}

extern "C" void kernel_launch(void* const* d_in, const int* in_sizes, int n_in,
                              void* d_out, int out_size, void* d_ws, size_t ws_size,
                              hipStream_t stream)
{
    const float* x   = (const float*)d_in[0];
    const float* krw = (const float*)d_in[1];
    const float* krx = (const float*)d_in[2];
    const float* kry = (const float*)d_in[3];
    const float* krz = (const float*)d_in[4];
    const float* kiw = (const float*)d_in[5];
    const float* kix = (const float*)d_in[6];
    const float* kiy = (const float*)d_in[7];
    const float* kiz = (const float*)d_in[8];

    // ws regions (34.6 MB each): [XT / PT] [WT] [Xs / P]
    const size_t R = (size_t)NBIN * 8192 * sizeof(u16);   // 34.6 MB
    u16* XT = (u16*)d_ws;
    u32* PT = (u32*)d_ws;                                  // alias: XT dead after contract
    u16* WT = (u16*)((char*)d_ws + R);
    u32* Xs = (u32*)((char*)d_ws + 2*R);
    u32* P  = Xs;                                          // alias: Xs dead after xpose
    float* out = (float*)d_out;

    prep_w_kernel<<<dim3(NBIN/16, 8), 256, 0, stream>>>(krw, krx, kry, krz,
                                                        kiw, kix, kiy, kiz, WT);
    fft_fwd_kernel<<<dim3(NIMG/4), 256, 0, stream>>>(x, Xs);
    xpose_x_kernel<<<dim3(128, NBIN/32), 256, 0, stream>>>(Xs, (u32*)XT);
    contract_kernel<<<dim3(NBIN), 256, 0, stream>>>(XT, WT, P);
    pxpose_kernel<<<dim3(NBIN/32, NIMG/32), 256, 0, stream>>>(P, PT);
    fft_inv_kernel<<<dim3(NIMG), 256, 0, stream>>>(PT, out);
}

// Round 9
// 122.806 us; speedup vs baseline: 1.7265x; 1.2110x over previous
//
#include <hip/hip_runtime.h>

#define FH 64
#define FW 64
#define NWF 33
#define NBIN (FH*NWF)      // 2112
#define NIMG 4096          // 4 * 32 * 32
#define PI2 6.283185307179586f

typedef unsigned short u16;
typedef unsigned int u32;
typedef __attribute__((ext_vector_type(8))) short bf16x8;
typedef __attribute__((ext_vector_type(8))) _Float16 f16x8;
typedef __attribute__((ext_vector_type(4))) unsigned short u16x4;
typedef __attribute__((ext_vector_type(4))) float f32x4;
typedef __attribute__((ext_vector_type(4))) int   i32x4;

__device__ __forceinline__ u16 f2bf(float f) {
    unsigned u = __float_as_uint(f);
    unsigned r = (u + 0x7FFFu + ((u >> 16) & 1u)) >> 16;   // RNE
    return (u16)r;
}
__device__ __forceinline__ u16 f2h(float f) {
    _Float16 h = (_Float16)f;
    return __builtin_bit_cast(u16, h);
}
__device__ __forceinline__ float2 upk(u32 v) {
    return make_float2(__uint_as_float(v << 16), __uint_as_float(v & 0xFFFF0000u));
}
__device__ __forceinline__ u32 pk(float2 v) {
    return (u32)f2bf(v.x) | ((u32)f2bf(v.y) << 16);
}
__device__ __forceinline__ f16x8 negh(f16x8 v) {
    i32x4 t = __builtin_bit_cast(i32x4, v);
    t ^= (int)0x80008000;
    return __builtin_bit_cast(f16x8, t);
}

// ---------------- forward rfft2 via MFMA-DFT: one wave per image ----------------
__global__ __launch_bounds__(256, 2) void fft_fwd_kernel(const float* __restrict__ x,
                                                         u32* __restrict__ Xs)
{
    __shared__ __align__(16) u16 mats[2][64*72];   // [cos/sin][a*72+b], symmetric
    __shared__ __align__(16) u16 wbuf[4][6912];    // per-wave: xb / S_T / sbin

    const int tid  = threadIdx.x;
    const int lane = tid & 63;
    const int wid  = tid >> 6;
    const int a16  = lane & 15;
    const int q    = lane >> 4;

    const int img = blockIdx.x * 4 + wid;          // qc*1024 + b*32 + ci
    const int qc = img >> 10;
    const int b  = (img >> 5) & 31;
    const int ci = img & 31;
    const float* __restrict__ src = x + ((size_t)b*128 + (size_t)qc*32 + ci) * (FH*FW);

    for (int t = tid; t < 4096; t += 256) {
        int a = t >> 6, bb = t & 63;
        float sn, cs;
        __sincosf(PI2 * (float)((a*bb) & 63) * (1.f/64.f), &sn, &cs);
        mats[0][a*72 + bb] = f2h(cs);
        mats[1][a*72 + bb] = f2h(sn);
    }
    u16* xb = wbuf[wid];
    for (int i = 0; i < 16; ++i) {
        int idx4 = i*64 + lane;
        float4 v = ((const float4*)src)[idx4];
        int h = idx4 >> 4, c4 = (idx4 & 15) * 4;
        u16x4 hv = { f2h(v.x), f2h(v.y), f2h(v.z), f2h(v.w) };
        *(u16x4*)&xb[h*64 + c4] = hv;
    }
    __syncthreads();

    f16x8 xf[4][2];
    #pragma unroll
    for (int mt = 0; mt < 4; ++mt)
        #pragma unroll
        for (int ks = 0; ks < 2; ++ks)
            xf[mt][ks] = *(const f16x8*)&xb[(16*mt + a16)*64 + ks*32 + q*8];
    __syncthreads();

    // step1: S_re = x*C64, S_im = -x*S64; store transposed S_T[ri][k][h], stride 72
    u16* ST = wbuf[wid];
    #pragma unroll
    for (int mt = 0; mt < 4; ++mt) {
        f32x4 are[3], aim[3];
        #pragma unroll
        for (int nt = 0; nt < 3; ++nt) { are[nt] = (f32x4){0,0,0,0}; aim[nt] = (f32x4){0,0,0,0}; }
        #pragma unroll
        for (int nt = 0; nt < 3; ++nt)
            #pragma unroll
            for (int ks = 0; ks < 2; ++ks) {
                const int rb = (16*nt + a16)*72 + ks*32 + q*8;
                f16x8 cf = *(const f16x8*)&mats[0][rb];
                f16x8 sf = *(const f16x8*)&mats[1][rb];
                are[nt] = __builtin_amdgcn_mfma_f32_16x16x32_f16(xf[mt][ks], cf, are[nt], 0, 0, 0);
                aim[nt] = __builtin_amdgcn_mfma_f32_16x16x32_f16(xf[mt][ks], negh(sf), aim[nt], 0, 0, 0);
            }
        const int hb = 16*mt + 4*q;
        #pragma unroll
        for (int nt = 0; nt < 3; ++nt) {
            u16x4 re4 = { f2h(are[nt][0]), f2h(are[nt][1]), f2h(are[nt][2]), f2h(are[nt][3]) };
            u16x4 im4 = { f2h(aim[nt][0]), f2h(aim[nt][1]), f2h(aim[nt][2]), f2h(aim[nt][3]) };
            *(u16x4*)&ST[(16*nt + a16)*72 + hb]        = re4;
            *(u16x4*)&ST[(48 + 16*nt + a16)*72 + hb]   = im4;
        }
    }
    __syncthreads();

    f16x8 bfr[2][3][2];
    #pragma unroll
    for (int ri = 0; ri < 2; ++ri)
        #pragma unroll
        for (int nt = 0; nt < 3; ++nt)
            #pragma unroll
            for (int ks = 0; ks < 2; ++ks)
                bfr[ri][nt][ks] = *(const f16x8*)&ST[(ri*48 + 16*nt + a16)*72 + ks*32 + q*8];
    __syncthreads();

    // X_re = C*S_re + S*S_im ; X_im = C*S_im - S*S_re; pack bf16 into sbin
    u32* sbin = (u32*)wbuf[wid];
    #pragma unroll
    for (int mt = 0; mt < 4; ++mt) {
        f16x8 cfa[2], sfa[2], nsf[2];
        #pragma unroll
        for (int ks = 0; ks < 2; ++ks) {
            const int rb = (16*mt + a16)*72 + ks*32 + q*8;
            cfa[ks] = *(const f16x8*)&mats[0][rb];
            sfa[ks] = *(const f16x8*)&mats[1][rb];
            nsf[ks] = negh(sfa[ks]);
        }
        #pragma unroll
        for (int nt = 0; nt < 3; ++nt) {
            f32x4 xre = (f32x4){0,0,0,0}, xim = (f32x4){0,0,0,0};
            #pragma unroll
            for (int ks = 0; ks < 2; ++ks) {
                xre = __builtin_amdgcn_mfma_f32_16x16x32_f16(cfa[ks], bfr[0][nt][ks], xre, 0, 0, 0);
                xre = __builtin_amdgcn_mfma_f32_16x16x32_f16(sfa[ks], bfr[1][nt][ks], xre, 0, 0, 0);
                xim = __builtin_amdgcn_mfma_f32_16x16x32_f16(cfa[ks], bfr[1][nt][ks], xim, 0, 0, 0);
                xim = __builtin_amdgcn_mfma_f32_16x16x32_f16(nsf[ks], bfr[0][nt][ks], xim, 0, 0, 0);
            }
            const int k = 16*nt + a16;
            if (k < 33) {
                #pragma unroll
                for (int r = 0; r < 4; ++r)
                    sbin[(16*mt + 4*q + r)*34 + k] = pk(make_float2(xre[r], xim[r]));
            }
        }
    }
    __syncthreads();

    u32* __restrict__ dst = Xs + (size_t)img * NBIN;
    for (int i = 0; i < 33; ++i) {
        int t = i*64 + lane;               // 33*64 = 2112 exactly
        int hf = t / 33;
        dst[t] = sbin[hf*34 + (t - hf*33)];
    }
}

// ---------------- transpose X: [img][bin] u32 -> [bin][q][ri][b][i] bf16 ----------------
__global__ __launch_bounds__(256) void xpose_x_kernel(const u32* __restrict__ Xs,
                                                      u32* __restrict__ XT)
{
    const int g    = blockIdx.x;        // q*32 + b
    const int bin0 = blockIdx.y * 32;
    __shared__ u32 tile[32][33];
    const int tid = threadIdx.x;
    #pragma unroll
    for (int it = 0; it < 4; ++it) {
        int e = tid + it*256;
        int imgL = e >> 5, binL = e & 31;
        tile[imgL][binL] = Xs[(size_t)(g*32 + imgL) * NBIN + bin0 + binL];
    }
    __syncthreads();
    const int q = g >> 5, b = g & 31;
    #pragma unroll
    for (int it = 0; it < 2; ++it) {
        int e = tid + it*256;          // 512 tasks: [binL][i-pair]
        int binL = e >> 4, pr = e & 15;
        u32 v0 = tile[pr*2][binL], v1 = tile[pr*2 + 1][binL];
        u32 re = (v0 & 0xFFFFu) | (v1 << 16);
        u32 im = (v0 >> 16) | (v1 & 0xFFFF0000u);
        size_t base = ((size_t)(bin0 + binL)*8 + q*2) * 512 + b*16 + pr;  // u32 units
        XT[base]       = re;
        XT[base + 512] = im;
    }
}

// ---------------- transpose W (tiled): [i][o][bin] f32 -> [bin][p][ri][o][i] bf16 ----------------
__global__ __launch_bounds__(256) void prep_w_kernel(
    const float* __restrict__ s0, const float* __restrict__ s1,
    const float* __restrict__ s2, const float* __restrict__ s3,
    const float* __restrict__ s4, const float* __restrict__ s5,
    const float* __restrict__ s6, const float* __restrict__ s7,
    u16* __restrict__ WT)
{
    const int bt = blockIdx.x;          // 66 bin tiles of 32
    const int a  = blockIdx.y >> 2;     // array 0..7 (kr_wxyz, ki_wxyz)
    const int o0 = (blockIdx.y & 3) * 8;
    const float* __restrict__ src =
        (a==0)?s0:(a==1)?s1:(a==2)?s2:(a==3)?s3:(a==4)?s4:(a==5)?s5:(a==6)?s6:s7;
    const int bin0 = bt * 32;
    __shared__ u16 lds2[32*264];        // [binL][chL], chL = oo*32 + i
    const int tid = threadIdx.x;

    #pragma unroll
    for (int it = 0; it < 8; ++it) {
        int e = tid + it*256;           // 2048 float4 tasks
        int f4 = e & 7, rt = e >> 3;    // rt 0..255
        int i = rt & 31, oo = rt >> 5;  // io = i*32 + o0+oo
        int io = i*32 + o0 + oo;
        float4 v = ((const float4*)src)[(size_t)io*(NBIN/4) + bt*8 + f4];
        int chL = oo*32 + i;
        int bb = f4*4;
        lds2[(bb+0)*264 + chL] = f2bf(v.x);
        lds2[(bb+1)*264 + chL] = f2bf(v.y);
        lds2[(bb+2)*264 + chL] = f2bf(v.z);
        lds2[(bb+3)*264 + chL] = f2bf(v.w);
    }
    __syncthreads();
    const int p = a & 3, ri = a >> 2;
    #pragma unroll
    for (int it = 0; it < 4; ++it) {
        int e = tid + it*256;           // 1024 bf16x8 tasks
        int binL = e >> 5, c8 = e & 31;
        bf16x8 v = *(const bf16x8*)&lds2[binL*264 + c8*8];
        size_t d = ((size_t)(bin0 + binL)*8 + p*2 + ri)*1024 + o0*32 + c8*8;
        *(bf16x8*)(WT + d) = v;
    }
}

// ---------------- per-bin quaternion contraction via MFMA ----------------
__global__ __launch_bounds__(256) void contract_kernel(
    const u16* __restrict__ XT, const u16* __restrict__ WT,
    u32* __restrict__ P)
{
    const int bid  = blockIdx.x;
    const int bin  = (bid & 7) * (NBIN/8) + (bid >> 3);   // chunked XCD swizzle
    const int wid  = threadIdx.x >> 6;
    const int lane = threadIdx.x & 63;
    const int bh = wid >> 1, oh = wid & 1;
    const int row = lane & 15, kg = lane >> 4;

    const u16* __restrict__ xb = XT + (size_t)bin * 8192;
    const u16* __restrict__ wb = WT + (size_t)bin * 8192;

    bf16x8 ax[4][2];
    #pragma unroll
    for (int q = 0; q < 4; ++q)
        #pragma unroll
        for (int ri = 0; ri < 2; ++ri)
            ax[q][ri] = *(const bf16x8*)(xb + ((q*2 + ri)*32 + bh*16 + row)*32 + kg*8);

    bf16x8 wpos[4][2], wneg[4][2];
    #pragma unroll
    for (int p = 0; p < 4; ++p)
        #pragma unroll
        for (int ri = 0; ri < 2; ++ri) {
            bf16x8 w = *(const bf16x8*)(wb + ((p*2 + ri)*32 + oh*16 + row)*32 + kg*8);
            wpos[p][ri] = w;
            i32x4 t = __builtin_bit_cast(i32x4, w);
            t ^= (int)0x80008000;
            wneg[p][ri] = __builtin_bit_cast(bf16x8, t);
        }

    f32x4 acc[4][2];
    #pragma unroll
    for (int c = 0; c < 4; ++c)
        #pragma unroll
        for (int ri = 0; ri < 2; ++ri)
            acc[c][ri] = (f32x4){0.f, 0.f, 0.f, 0.f};

    constexpr int PI_[4][4] = {{0,1,2,3},{1,0,3,2},{2,3,0,1},{3,2,1,0}};
    constexpr int SG_[4][4] = {{1,-1,-1,-1},{1,1,-1,1},{1,1,1,-1},{1,-1,1,1}};
    #pragma unroll
    for (int c = 0; c < 4; ++c)
        #pragma unroll
        for (int q = 0; q < 4; ++q) {
            const int  p   = PI_[c][q];
            const bool pos = SG_[c][q] > 0;
            bf16x8 wr_s = pos ? wpos[p][0] : wneg[p][0];
            bf16x8 wi_s = pos ? wpos[p][1] : wneg[p][1];
            bf16x8 wi_m = pos ? wneg[p][1] : wpos[p][1];
            acc[c][0] = __builtin_amdgcn_mfma_f32_16x16x32_bf16(ax[q][0], wr_s, acc[c][0], 0, 0, 0);
            acc[c][0] = __builtin_amdgcn_mfma_f32_16x16x32_bf16(ax[q][1], wi_m, acc[c][0], 0, 0, 0);
            acc[c][1] = __builtin_amdgcn_mfma_f32_16x16x32_bf16(ax[q][1], wr_s, acc[c][1], 0, 0, 0);
            acc[c][1] = __builtin_amdgcn_mfma_f32_16x16x32_bf16(ax[q][0], wi_s, acc[c][1], 0, 0, 0);
        }

    u32* __restrict__ dst = P + (size_t)bin * 4096;
    #pragma unroll
    for (int c = 0; c < 4; ++c)
        #pragma unroll
        for (int r = 0; r < 4; ++r) {
            int b_ = bh*16 + kg*4 + r;
            int o  = oh*16 + row;
            dst[c*1024 + b_*32 + o] = pk(make_float2(acc[c][0][r], acc[c][1][r]));
        }
}

// ---------------- transpose P: [bin][img] u32 -> PT[img][bin] u32 ----------------
__global__ __launch_bounds__(256) void pxpose_kernel(const u32* __restrict__ P,
                                                     u32* __restrict__ PT)
{
    const int bin0 = blockIdx.x * 32;
    const int img0 = blockIdx.y * 32;
    __shared__ u32 tile[32][33];
    const int tid = threadIdx.x;
    #pragma unroll
    for (int it = 0; it < 4; ++it) {
        int e = tid + it*256;
        int bi = e >> 5, im = e & 31;
        tile[bi][im] = P[(size_t)(bin0 + bi) * 4096 + img0 + im];
    }
    __syncthreads();
    #pragma unroll
    for (int it = 0; it < 4; ++it) {
        int e = tid + it*256;
        int im = e >> 5, bi = e & 31;
        PT[(size_t)(img0 + im) * NBIN + bin0 + bi] = tile[bi][im];
    }
}

// ---------------- inverse rfft2 via MFMA-DFT: one wave per image ----------------
// step1: T^T = E^T*(C+iS) (h-inverse); a_m/4096 irfft weights folded into f16 T.
// step2: out = T_re*C - T_im*S (w-inverse, real part).
__global__ __launch_bounds__(256, 2) void fft_inv_kernel(const u32* __restrict__ PT,
                                                         float* __restrict__ out)
{
    __shared__ __align__(16) u16 mats[2][64*72];   // cos/sin(+2pi ab/64), symmetric
    __shared__ __align__(16) u16 wbuf[4][7168];    // per-wave: ET (2x48x72) / T (2x64x56)

    const int tid  = threadIdx.x;
    const int lane = tid & 63;
    const int wid  = tid >> 6;
    const int a16  = lane & 15;
    const int q    = lane >> 4;

    const int img = blockIdx.x * 4 + wid;          // c*1024 + b*32 + oc
    const int c  = img >> 10;
    const int b  = (img >> 5) & 31;
    const int oc = img & 31;

    for (int t = tid; t < 4096; t += 256) {
        int a = t >> 6, bb = t & 63;
        float sn, cs;
        __sincosf(PI2 * (float)((a*bb) & 63) * (1.f/64.f), &sn, &cs);
        mats[0][a*72 + bb] = f2h(cs);
        mats[1][a*72 + bb] = f2h(sn);
    }

    // stage E^T: ETre[k][hf], ETim[k][hf], stride 72.
    // CRITICAL: rows k=33..47 feed MFMA as A-rows -> must be ZERO, not stale LDS.
    u16* ETre = wbuf[wid];
    u16* ETim = wbuf[wid] + 48*72;
    for (int j = 33*72 + lane; j < 48*72; j += 64) {
        ETre[j] = 0;
        ETim[j] = 0;
    }
    const u32* __restrict__ srcP = PT + (size_t)img * NBIN;
    for (int i = 0; i < 33; ++i) {
        int t = i*64 + lane;
        int hf = t / 33, k = t - hf*33;
        float2 v = upk(srcP[t]);
        ETre[k*72 + hf] = f2h(v.x);
        ETim[k*72 + hf] = f2h(v.y);
    }
    __syncthreads();

    // preload E^T A-fragments (ET dead afterwards)
    f16x8 ere[3][2], eim[3][2];
    #pragma unroll
    for (int mt = 0; mt < 3; ++mt)
        #pragma unroll
        for (int ks = 0; ks < 2; ++ks) {
            ere[mt][ks] = *(const f16x8*)&ETre[(16*mt + a16)*72 + ks*32 + q*8];
            eim[mt][ks] = *(const f16x8*)&ETim[(16*mt + a16)*72 + ks*32 + q*8];
        }
    __syncthreads();

    // step1: T_re^T = Ere*C - Eim*S ; T_im^T = Ere*S + Eim*C; D-layout writes T[h][m]
    u16* Tre = wbuf[wid];              // [64][56]
    u16* Tim = wbuf[wid] + 64*56;
    #pragma unroll
    for (int mt = 0; mt < 3; ++mt) {
        #pragma unroll
        for (int nt = 0; nt < 4; ++nt) {
            f32x4 tre = (f32x4){0,0,0,0}, tim = (f32x4){0,0,0,0};
            #pragma unroll
            for (int ks = 0; ks < 2; ++ks) {
                const int rb = (16*nt + a16)*72 + ks*32 + q*8;
                f16x8 cf = *(const f16x8*)&mats[0][rb];
                f16x8 sf = *(const f16x8*)&mats[1][rb];
                tre = __builtin_amdgcn_mfma_f32_16x16x32_f16(ere[mt][ks], cf, tre, 0, 0, 0);
                tre = __builtin_amdgcn_mfma_f32_16x16x32_f16(eim[mt][ks], negh(sf), tre, 0, 0, 0);
                tim = __builtin_amdgcn_mfma_f32_16x16x32_f16(ere[mt][ks], sf, tim, 0, 0, 0);
                tim = __builtin_amdgcn_mfma_f32_16x16x32_f16(eim[mt][ks], cf, tim, 0, 0, 0);
            }
            const int m0 = 16*mt + 4*q;        // row = m, col = h
            u16x4 r4, i4;
            #pragma unroll
            for (int r = 0; r < 4; ++r) {
                int m = m0 + r;
                float s = (m == 0 || m == 32) ? (1.f/4096.f) : (2.f/4096.f);
                r4[r] = (m < 33) ? f2h(tre[r] * s) : (u16)0;   // literal 0, not value*0
                i4[r] = (m < 33) ? f2h(tim[r] * s) : (u16)0;
            }
            *(u16x4*)&Tre[(16*nt + a16)*56 + m0] = r4;
            *(u16x4*)&Tim[(16*nt + a16)*56 + m0] = i4;
        }
    }
    __syncthreads();

    // step2: out[h][w] = sum_m Tre[h][m]*C[w][m] - Tim[h][m]*S[w][m]
    float* __restrict__ dst = out + ((size_t)b*128 + (size_t)c*32 + oc) * (FH*FW);
    #pragma unroll
    for (int mt = 0; mt < 4; ++mt) {
        f16x8 tfr[2], tfi[2];
        #pragma unroll
        for (int ks = 0; ks < 2; ++ks) {
            const int mbase = ks*32 + q*8;
            if (mbase < 48) {
                tfr[ks] = *(const f16x8*)&Tre[(16*mt + a16)*56 + mbase];
                tfi[ks] = *(const f16x8*)&Tim[(16*mt + a16)*56 + mbase];
            } else {
                tfr[ks] = (f16x8){0,0,0,0,0,0,0,0};
                tfi[ks] = (f16x8){0,0,0,0,0,0,0,0};
            }
        }
        #pragma unroll
        for (int nt = 0; nt < 4; ++nt) {
            f32x4 acc = (f32x4){0,0,0,0};
            #pragma unroll
            for (int ks = 0; ks < 2; ++ks) {
                const int rb = (16*nt + a16)*72 + ks*32 + q*8;
                f16x8 cf = *(const f16x8*)&mats[0][rb];
                f16x8 sf = *(const f16x8*)&mats[1][rb];
                acc = __builtin_amdgcn_mfma_f32_16x16x32_f16(tfr[ks], cf, acc, 0, 0, 0);
                acc = __builtin_amdgcn_mfma_f32_16x16x32_f16(tfi[ks], negh(sf), acc, 0, 0, 0);
            }
            // col = w = 16nt+a16, row = h = 16mt+4q+r
            #pragma unroll
            for (int r = 0; r < 4; ++r)
                dst[(16*mt + 4*q + r)*64 + 16*nt + a16] = acc[r];
        }
    }
}

extern "C" void kernel_launch(void* const* d_in, const int* in_sizes, int n_in,
                              void* d_out, int out_size, void* d_ws, size_t ws_size,
                              hipStream_t stream)
{
    const float* x   = (const float*)d_in[0];
    const float* krw = (const float*)d_in[1];
    const float* krx = (const float*)d_in[2];
    const float* kry = (const float*)d_in[3];
    const float* krz = (const float*)d_in[4];
    const float* kiw = (const float*)d_in[5];
    const float* kix = (const float*)d_in[6];
    const float* kiy = (const float*)d_in[7];
    const float* kiz = (const float*)d_in[8];

    // ws regions (34.6 MB each): [XT / PT] [WT] [Xs / P]
    const size_t R = (size_t)NBIN * 8192 * sizeof(u16);   // 34.6 MB
    u16* XT = (u16*)d_ws;
    u32* PT = (u32*)d_ws;                                  // alias: XT dead after contract
    u16* WT = (u16*)((char*)d_ws + R);
    u32* Xs = (u32*)((char*)d_ws + 2*R);
    u32* P  = Xs;                                          // alias: Xs dead after xpose
    float* out = (float*)d_out;

    prep_w_kernel<<<dim3(66, 32), 256, 0, stream>>>(krw, krx, kry, krz,
                                                    kiw, kix, kiy, kiz, WT);
    fft_fwd_kernel<<<dim3(NIMG/4), 256, 0, stream>>>(x, Xs);
    xpose_x_kernel<<<dim3(128, NBIN/32), 256, 0, stream>>>(Xs, (u32*)XT);
    contract_kernel<<<dim3(NBIN), 256, 0, stream>>>(XT, WT, P);
    pxpose_kernel<<<dim3(NBIN/32, NIMG/32), 256, 0, stream>>>(P, PT);
    fft_inv_kernel<<<dim3(NIMG/4), 256, 0, stream>>>(PT, out);
}

// Round 10
// 119.772 us; speedup vs baseline: 1.7702x; 1.0253x over previous
//
#include <hip/hip_runtime.h>

#define FH 64
#define FW 64
#define NWF 33
#define NBIN (FH*NWF)      // 2112
#define NIMG 4096          // 4 * 32 * 32
#define PI2 6.283185307179586f

typedef unsigned short u16;
typedef unsigned int u32;
typedef __attribute__((ext_vector_type(8))) short bf16x8;
typedef __attribute__((ext_vector_type(8))) _Float16 f16x8;
typedef __attribute__((ext_vector_type(4))) unsigned short u16x4;
typedef __attribute__((ext_vector_type(4))) float f32x4;
typedef __attribute__((ext_vector_type(4))) int   i32x4;

__device__ __forceinline__ u16 f2bf(float f) {
    unsigned u = __float_as_uint(f);
    unsigned r = (u + 0x7FFFu + ((u >> 16) & 1u)) >> 16;   // RNE
    return (u16)r;
}
__device__ __forceinline__ u16 f2h(float f) {
    _Float16 h = (_Float16)f;
    return __builtin_bit_cast(u16, h);
}
__device__ __forceinline__ float2 upk(u32 v) {
    return make_float2(__uint_as_float(v << 16), __uint_as_float(v & 0xFFFF0000u));
}
__device__ __forceinline__ u32 pk(float2 v) {
    return (u32)f2bf(v.x) | ((u32)f2bf(v.y) << 16);
}
__device__ __forceinline__ f16x8 negh(f16x8 v) {
    i32x4 t = __builtin_bit_cast(i32x4, v);
    t ^= (int)0x80008000;
    return __builtin_bit_cast(f16x8, t);
}

// ---------------- forward rfft2 via MFMA-DFT: TWO waves per image ----------------
__global__ __launch_bounds__(512, 4) void fft_fwd_kernel(const float* __restrict__ x,
                                                         u32* __restrict__ Xs)
{
    __shared__ __align__(16) u16 mats[2][64*72];   // [cos/sin][a*72+b], symmetric
    __shared__ __align__(16) u16 wbuf[4][6912];    // per-image: xb / S_T / sbin

    const int tid  = threadIdx.x;
    const int lane = tid & 63;
    const int wid  = tid >> 6;         // 0..7
    const int slot = wid >> 1;         // image slot 0..3
    const int half = wid & 1;          // M-split half
    const int ltid = (half << 6) | lane;  // image-local tid 0..127
    const int a16  = lane & 15;
    const int q    = lane >> 4;

    const int img = blockIdx.x * 4 + slot;         // qc*1024 + b*32 + ci
    const int qc = img >> 10;
    const int b  = (img >> 5) & 31;
    const int ci = img & 31;
    const float* __restrict__ src = x + ((size_t)b*128 + (size_t)qc*32 + ci) * (FH*FW);

    for (int t = tid; t < 4096; t += 512) {
        int a = t >> 6, bb = t & 63;
        float sn, cs;
        __sincosf(PI2 * (float)((a*bb) & 63) * (1.f/64.f), &sn, &cs);
        mats[0][a*72 + bb] = f2h(cs);
        mats[1][a*72 + bb] = f2h(sn);
    }
    u16* xb = wbuf[slot];
    for (int i = 0; i < 8; ++i) {
        int idx4 = i*128 + ltid;
        float4 v = ((const float4*)src)[idx4];
        int h = idx4 >> 4, c4 = (idx4 & 15) * 4;
        u16x4 hv = { f2h(v.x), f2h(v.y), f2h(v.z), f2h(v.w) };
        *(u16x4*)&xb[h*64 + c4] = hv;
    }
    __syncthreads();

    // preload this wave's x A-fragments (mt = 2*half + mtl)
    f16x8 xf[2][2];
    #pragma unroll
    for (int mtl = 0; mtl < 2; ++mtl)
        #pragma unroll
        for (int ks = 0; ks < 2; ++ks)
            xf[mtl][ks] = *(const f16x8*)&xb[(16*(2*half + mtl) + a16)*64 + ks*32 + q*8];
    __syncthreads();

    // step1: S_re = x*C64, S_im = -x*S64; store transposed S_T[ri][k][h], stride 72
    u16* ST = wbuf[slot];
    #pragma unroll
    for (int mtl = 0; mtl < 2; ++mtl) {
        const int mt = 2*half + mtl;
        f32x4 are[3], aim[3];
        #pragma unroll
        for (int nt = 0; nt < 3; ++nt) { are[nt] = (f32x4){0,0,0,0}; aim[nt] = (f32x4){0,0,0,0}; }
        #pragma unroll
        for (int nt = 0; nt < 3; ++nt)
            #pragma unroll
            for (int ks = 0; ks < 2; ++ks) {
                const int rb = (16*nt + a16)*72 + ks*32 + q*8;
                f16x8 cf = *(const f16x8*)&mats[0][rb];
                f16x8 sf = *(const f16x8*)&mats[1][rb];
                are[nt] = __builtin_amdgcn_mfma_f32_16x16x32_f16(xf[mtl][ks], cf, are[nt], 0, 0, 0);
                aim[nt] = __builtin_amdgcn_mfma_f32_16x16x32_f16(xf[mtl][ks], negh(sf), aim[nt], 0, 0, 0);
            }
        const int hb = 16*mt + 4*q;
        #pragma unroll
        for (int nt = 0; nt < 3; ++nt) {
            u16x4 re4 = { f2h(are[nt][0]), f2h(are[nt][1]), f2h(are[nt][2]), f2h(are[nt][3]) };
            u16x4 im4 = { f2h(aim[nt][0]), f2h(aim[nt][1]), f2h(aim[nt][2]), f2h(aim[nt][3]) };
            *(u16x4*)&ST[(16*nt + a16)*72 + hb]        = re4;
            *(u16x4*)&ST[(48 + 16*nt + a16)*72 + hb]   = im4;
        }
    }
    __syncthreads();

    f16x8 bfr[2][3][2];
    #pragma unroll
    for (int ri = 0; ri < 2; ++ri)
        #pragma unroll
        for (int nt = 0; nt < 3; ++nt)
            #pragma unroll
            for (int ks = 0; ks < 2; ++ks)
                bfr[ri][nt][ks] = *(const f16x8*)&ST[(ri*48 + 16*nt + a16)*72 + ks*32 + q*8];
    __syncthreads();

    // step2: X_re = C*S_re + S*S_im ; X_im = C*S_im - S*S_re; pack bf16 into sbin
    u32* sbin = (u32*)wbuf[slot];
    #pragma unroll
    for (int mtl = 0; mtl < 2; ++mtl) {
        const int mt = 2*half + mtl;
        f16x8 cfa[2], sfa[2], nsf[2];
        #pragma unroll
        for (int ks = 0; ks < 2; ++ks) {
            const int rb = (16*mt + a16)*72 + ks*32 + q*8;
            cfa[ks] = *(const f16x8*)&mats[0][rb];
            sfa[ks] = *(const f16x8*)&mats[1][rb];
            nsf[ks] = negh(sfa[ks]);
        }
        #pragma unroll
        for (int nt = 0; nt < 3; ++nt) {
            f32x4 xre = (f32x4){0,0,0,0}, xim = (f32x4){0,0,0,0};
            #pragma unroll
            for (int ks = 0; ks < 2; ++ks) {
                xre = __builtin_amdgcn_mfma_f32_16x16x32_f16(cfa[ks], bfr[0][nt][ks], xre, 0, 0, 0);
                xre = __builtin_amdgcn_mfma_f32_16x16x32_f16(sfa[ks], bfr[1][nt][ks], xre, 0, 0, 0);
                xim = __builtin_amdgcn_mfma_f32_16x16x32_f16(cfa[ks], bfr[1][nt][ks], xim, 0, 0, 0);
                xim = __builtin_amdgcn_mfma_f32_16x16x32_f16(nsf[ks], bfr[0][nt][ks], xim, 0, 0, 0);
            }
            const int k = 16*nt + a16;
            if (k < 33) {
                #pragma unroll
                for (int r = 0; r < 4; ++r)
                    sbin[(16*mt + 4*q + r)*34 + k] = pk(make_float2(xre[r], xim[r]));
            }
        }
    }
    __syncthreads();

    u32* __restrict__ dst = Xs + (size_t)img * NBIN;
    for (int i = 0; i < 17; ++i) {
        int t = i*128 + ltid;
        if (t < NBIN) {
            int hf = t / 33;
            dst[t] = sbin[hf*34 + (t - hf*33)];
        }
    }
}

// ---------------- transpose X: [img][bin] u32 -> [bin][q][ri][b][i] bf16 ----------------
__global__ __launch_bounds__(256) void xpose_x_kernel(const u32* __restrict__ Xs,
                                                      u32* __restrict__ XT)
{
    const int g    = blockIdx.x;        // q*32 + b
    const int bin0 = blockIdx.y * 32;
    __shared__ u32 tile[32][33];
    const int tid = threadIdx.x;
    #pragma unroll
    for (int it = 0; it < 4; ++it) {
        int e = tid + it*256;
        int imgL = e >> 5, binL = e & 31;
        tile[imgL][binL] = Xs[(size_t)(g*32 + imgL) * NBIN + bin0 + binL];
    }
    __syncthreads();
    const int q = g >> 5, b = g & 31;
    #pragma unroll
    for (int it = 0; it < 2; ++it) {
        int e = tid + it*256;          // 512 tasks: [binL][i-pair]
        int binL = e >> 4, pr = e & 15;
        u32 v0 = tile[pr*2][binL], v1 = tile[pr*2 + 1][binL];
        u32 re = (v0 & 0xFFFFu) | (v1 << 16);
        u32 im = (v0 >> 16) | (v1 & 0xFFFF0000u);
        size_t base = ((size_t)(bin0 + binL)*8 + q*2) * 512 + b*16 + pr;  // u32 units
        XT[base]       = re;
        XT[base + 512] = im;
    }
}

// ---------------- transpose W (tiled): [i][o][bin] f32 -> [bin][p][ri][o][i] bf16 ----------------
__global__ __launch_bounds__(256) void prep_w_kernel(
    const float* __restrict__ s0, const float* __restrict__ s1,
    const float* __restrict__ s2, const float* __restrict__ s3,
    const float* __restrict__ s4, const float* __restrict__ s5,
    const float* __restrict__ s6, const float* __restrict__ s7,
    u16* __restrict__ WT)
{
    const int bt = blockIdx.x;          // 66 bin tiles of 32
    const int a  = blockIdx.y >> 2;     // array 0..7 (kr_wxyz, ki_wxyz)
    const int o0 = (blockIdx.y & 3) * 8;
    const float* __restrict__ src =
        (a==0)?s0:(a==1)?s1:(a==2)?s2:(a==3)?s3:(a==4)?s4:(a==5)?s5:(a==6)?s6:s7;
    const int bin0 = bt * 32;
    __shared__ u16 lds2[32*264];        // [binL][chL], chL = oo*32 + i
    const int tid = threadIdx.x;

    #pragma unroll
    for (int it = 0; it < 8; ++it) {
        int e = tid + it*256;           // 2048 float4 tasks
        int f4 = e & 7, rt = e >> 3;    // rt 0..255
        int i = rt & 31, oo = rt >> 5;  // io = i*32 + o0+oo
        int io = i*32 + o0 + oo;
        float4 v = ((const float4*)src)[(size_t)io*(NBIN/4) + bt*8 + f4];
        int chL = oo*32 + i;
        int bb = f4*4;
        lds2[(bb+0)*264 + chL] = f2bf(v.x);
        lds2[(bb+1)*264 + chL] = f2bf(v.y);
        lds2[(bb+2)*264 + chL] = f2bf(v.z);
        lds2[(bb+3)*264 + chL] = f2bf(v.w);
    }
    __syncthreads();
    const int p = a & 3, ri = a >> 2;
    #pragma unroll
    for (int it = 0; it < 4; ++it) {
        int e = tid + it*256;           // 1024 bf16x8 tasks
        int binL = e >> 5, c8 = e & 31;
        bf16x8 v = *(const bf16x8*)&lds2[binL*264 + c8*8];
        size_t d = ((size_t)(bin0 + binL)*8 + p*2 + ri)*1024 + o0*32 + c8*8;
        *(bf16x8*)(WT + d) = v;
    }
}

// ---------------- per-bin quaternion contraction via MFMA ----------------
__global__ __launch_bounds__(256) void contract_kernel(
    const u16* __restrict__ XT, const u16* __restrict__ WT,
    u32* __restrict__ P)
{
    const int bid  = blockIdx.x;
    const int bin  = (bid & 7) * (NBIN/8) + (bid >> 3);   // chunked XCD swizzle
    const int wid  = threadIdx.x >> 6;
    const int lane = threadIdx.x & 63;
    const int bh = wid >> 1, oh = wid & 1;
    const int row = lane & 15, kg = lane >> 4;

    const u16* __restrict__ xb = XT + (size_t)bin * 8192;
    const u16* __restrict__ wb = WT + (size_t)bin * 8192;

    bf16x8 ax[4][2];
    #pragma unroll
    for (int q = 0; q < 4; ++q)
        #pragma unroll
        for (int ri = 0; ri < 2; ++ri)
            ax[q][ri] = *(const bf16x8*)(xb + ((q*2 + ri)*32 + bh*16 + row)*32 + kg*8);

    bf16x8 wpos[4][2], wneg[4][2];
    #pragma unroll
    for (int p = 0; p < 4; ++p)
        #pragma unroll
        for (int ri = 0; ri < 2; ++ri) {
            bf16x8 w = *(const bf16x8*)(wb + ((p*2 + ri)*32 + oh*16 + row)*32 + kg*8);
            wpos[p][ri] = w;
            i32x4 t = __builtin_bit_cast(i32x4, w);
            t ^= (int)0x80008000;
            wneg[p][ri] = __builtin_bit_cast(bf16x8, t);
        }

    f32x4 acc[4][2];
    #pragma unroll
    for (int c = 0; c < 4; ++c)
        #pragma unroll
        for (int ri = 0; ri < 2; ++ri)
            acc[c][ri] = (f32x4){0.f, 0.f, 0.f, 0.f};

    constexpr int PI_[4][4] = {{0,1,2,3},{1,0,3,2},{2,3,0,1},{3,2,1,0}};
    constexpr int SG_[4][4] = {{1,-1,-1,-1},{1,1,-1,1},{1,1,1,-1},{1,-1,1,1}};
    #pragma unroll
    for (int c = 0; c < 4; ++c)
        #pragma unroll
        for (int q = 0; q < 4; ++q) {
            const int  p   = PI_[c][q];
            const bool pos = SG_[c][q] > 0;
            bf16x8 wr_s = pos ? wpos[p][0] : wneg[p][0];
            bf16x8 wi_s = pos ? wpos[p][1] : wneg[p][1];
            bf16x8 wi_m = pos ? wneg[p][1] : wpos[p][1];
            acc[c][0] = __builtin_amdgcn_mfma_f32_16x16x32_bf16(ax[q][0], wr_s, acc[c][0], 0, 0, 0);
            acc[c][0] = __builtin_amdgcn_mfma_f32_16x16x32_bf16(ax[q][1], wi_m, acc[c][0], 0, 0, 0);
            acc[c][1] = __builtin_amdgcn_mfma_f32_16x16x32_bf16(ax[q][1], wr_s, acc[c][1], 0, 0, 0);
            acc[c][1] = __builtin_amdgcn_mfma_f32_16x16x32_bf16(ax[q][0], wi_s, acc[c][1], 0, 0, 0);
        }

    u32* __restrict__ dst = P + (size_t)bin * 4096;
    #pragma unroll
    for (int c = 0; c < 4; ++c)
        #pragma unroll
        for (int r = 0; r < 4; ++r) {
            int b_ = bh*16 + kg*4 + r;
            int o  = oh*16 + row;
            dst[c*1024 + b_*32 + o] = pk(make_float2(acc[c][0][r], acc[c][1][r]));
        }
}

// ---------------- transpose P: [bin][img] u32 -> PT[img][bin] u32 ----------------
__global__ __launch_bounds__(256) void pxpose_kernel(const u32* __restrict__ P,
                                                     u32* __restrict__ PT)
{
    const int bin0 = blockIdx.x * 32;
    const int img0 = blockIdx.y * 32;
    __shared__ u32 tile[32][33];
    const int tid = threadIdx.x;
    #pragma unroll
    for (int it = 0; it < 4; ++it) {
        int e = tid + it*256;
        int bi = e >> 5, im = e & 31;
        tile[bi][im] = P[(size_t)(bin0 + bi) * 4096 + img0 + im];
    }
    __syncthreads();
    #pragma unroll
    for (int it = 0; it < 4; ++it) {
        int e = tid + it*256;
        int im = e >> 5, bi = e & 31;
        PT[(size_t)(img0 + im) * NBIN + bin0 + bi] = tile[bi][im];
    }
}

// ---------------- inverse rfft2 via MFMA-DFT: TWO waves per image ----------------
__global__ __launch_bounds__(512, 4) void fft_inv_kernel(const u32* __restrict__ PT,
                                                         float* __restrict__ out)
{
    __shared__ __align__(16) u16 mats[2][64*72];   // cos/sin(+2pi ab/64), symmetric
    __shared__ __align__(16) u16 wbuf[4][7168];    // per-image: ET (2x48x72) / T (2x64x56)

    const int tid  = threadIdx.x;
    const int lane = tid & 63;
    const int wid  = tid >> 6;
    const int slot = wid >> 1;
    const int half = wid & 1;
    const int ltid = (half << 6) | lane;
    const int a16  = lane & 15;
    const int q    = lane >> 4;

    const int img = blockIdx.x * 4 + slot;         // c*1024 + b*32 + oc
    const int c  = img >> 10;
    const int b  = (img >> 5) & 31;
    const int oc = img & 31;

    for (int t = tid; t < 4096; t += 512) {
        int a = t >> 6, bb = t & 63;
        float sn, cs;
        __sincosf(PI2 * (float)((a*bb) & 63) * (1.f/64.f), &sn, &cs);
        mats[0][a*72 + bb] = f2h(cs);
        mats[1][a*72 + bb] = f2h(sn);
    }

    // stage E^T: ETre[k][hf], ETim[k][hf], stride 72. Rows k=33..47 MUST be zero.
    u16* ETre = wbuf[slot];
    u16* ETim = wbuf[slot] + 48*72;
    for (int j = 33*72 + ltid; j < 48*72; j += 128) {
        ETre[j] = 0;
        ETim[j] = 0;
    }
    const u32* __restrict__ srcP = PT + (size_t)img * NBIN;
    for (int i = 0; i < 17; ++i) {
        int t = i*128 + ltid;
        if (t < NBIN) {
            int hf = t / 33, k = t - hf*33;
            float2 v = upk(srcP[t]);
            ETre[k*72 + hf] = f2h(v.x);
            ETim[k*72 + hf] = f2h(v.y);
        }
    }
    __syncthreads();

    // preload this wave's E^T A-fragments (mt = 2*half + mtl, valid mt < 3)
    f16x8 ere[2][2], eim[2][2];
    #pragma unroll
    for (int mtl = 0; mtl < 2; ++mtl) {
        const int mt = 2*half + mtl;
        if (mt < 3) {
            #pragma unroll
            for (int ks = 0; ks < 2; ++ks) {
                ere[mtl][ks] = *(const f16x8*)&ETre[(16*mt + a16)*72 + ks*32 + q*8];
                eim[mtl][ks] = *(const f16x8*)&ETim[(16*mt + a16)*72 + ks*32 + q*8];
            }
        }
    }
    __syncthreads();

    // step1: T_re^T = Ere*C - Eim*S ; T_im^T = Ere*S + Eim*C; D-layout writes T[h][m]
    u16* Tre = wbuf[slot];             // [64][56]
    u16* Tim = wbuf[slot] + 64*56;
    #pragma unroll
    for (int mtl = 0; mtl < 2; ++mtl) {
        const int mt = 2*half + mtl;
        if (mt < 3) {
            #pragma unroll
            for (int nt = 0; nt < 4; ++nt) {
                f32x4 tre = (f32x4){0,0,0,0}, tim = (f32x4){0,0,0,0};
                #pragma unroll
                for (int ks = 0; ks < 2; ++ks) {
                    const int rb = (16*nt + a16)*72 + ks*32 + q*8;
                    f16x8 cf = *(const f16x8*)&mats[0][rb];
                    f16x8 sf = *(const f16x8*)&mats[1][rb];
                    tre = __builtin_amdgcn_mfma_f32_16x16x32_f16(ere[mtl][ks], cf, tre, 0, 0, 0);
                    tre = __builtin_amdgcn_mfma_f32_16x16x32_f16(eim[mtl][ks], negh(sf), tre, 0, 0, 0);
                    tim = __builtin_amdgcn_mfma_f32_16x16x32_f16(ere[mtl][ks], sf, tim, 0, 0, 0);
                    tim = __builtin_amdgcn_mfma_f32_16x16x32_f16(eim[mtl][ks], cf, tim, 0, 0, 0);
                }
                const int m0 = 16*mt + 4*q;        // row = m, col = h
                u16x4 r4, i4;
                #pragma unroll
                for (int r = 0; r < 4; ++r) {
                    int m = m0 + r;
                    float s = (m == 0 || m == 32) ? (1.f/4096.f) : (2.f/4096.f);
                    r4[r] = (m < 33) ? f2h(tre[r] * s) : (u16)0;
                    i4[r] = (m < 33) ? f2h(tim[r] * s) : (u16)0;
                }
                *(u16x4*)&Tre[(16*nt + a16)*56 + m0] = r4;
                *(u16x4*)&Tim[(16*nt + a16)*56 + m0] = i4;
            }
        }
    }
    __syncthreads();

    // step2: out[h][w] = sum_m Tre[h][m]*C[w][m] - Tim[h][m]*S[w][m]
    float* __restrict__ dst = out + ((size_t)b*128 + (size_t)c*32 + oc) * (FH*FW);
    #pragma unroll
    for (int mtl = 0; mtl < 2; ++mtl) {
        const int mt = 2*half + mtl;
        f16x8 tfr[2], tfi[2];
        #pragma unroll
        for (int ks = 0; ks < 2; ++ks) {
            const int mbase = ks*32 + q*8;
            if (mbase < 48) {
                tfr[ks] = *(const f16x8*)&Tre[(16*mt + a16)*56 + mbase];
                tfi[ks] = *(const f16x8*)&Tim[(16*mt + a16)*56 + mbase];
            } else {
                tfr[ks] = (f16x8){0,0,0,0,0,0,0,0};
                tfi[ks] = (f16x8){0,0,0,0,0,0,0,0};
            }
        }
        #pragma unroll
        for (int nt = 0; nt < 4; ++nt) {
            f32x4 acc = (f32x4){0,0,0,0};
            #pragma unroll
            for (int ks = 0; ks < 2; ++ks) {
                const int rb = (16*nt + a16)*72 + ks*32 + q*8;
                f16x8 cf = *(const f16x8*)&mats[0][rb];
                f16x8 sf = *(const f16x8*)&mats[1][rb];
                acc = __builtin_amdgcn_mfma_f32_16x16x32_f16(tfr[ks], cf, acc, 0, 0, 0);
                acc = __builtin_amdgcn_mfma_f32_16x16x32_f16(tfi[ks], negh(sf), acc, 0, 0, 0);
            }
            // col = w = 16nt+a16, row = h = 16mt+4q+r
            #pragma unroll
            for (int r = 0; r < 4; ++r)
                dst[(16*mt + 4*q + r)*64 + 16*nt + a16] = acc[r];
        }
    }
}

extern "C" void kernel_launch(void* const* d_in, const int* in_sizes, int n_in,
                              void* d_out, int out_size, void* d_ws, size_t ws_size,
                              hipStream_t stream)
{
    const float* x   = (const float*)d_in[0];
    const float* krw = (const float*)d_in[1];
    const float* krx = (const float*)d_in[2];
    const float* kry = (const float*)d_in[3];
    const float* krz = (const float*)d_in[4];
    const float* kiw = (const float*)d_in[5];
    const float* kix = (const float*)d_in[6];
    const float* kiy = (const float*)d_in[7];
    const float* kiz = (const float*)d_in[8];

    // ws regions (34.6 MB each): [XT / PT] [WT] [Xs / P]
    const size_t R = (size_t)NBIN * 8192 * sizeof(u16);   // 34.6 MB
    u16* XT = (u16*)d_ws;
    u32* PT = (u32*)d_ws;                                  // alias: XT dead after contract
    u16* WT = (u16*)((char*)d_ws + R);
    u32* Xs = (u32*)((char*)d_ws + 2*R);
    u32* P  = Xs;                                          // alias: Xs dead after xpose
    float* out = (float*)d_out;

    prep_w_kernel<<<dim3(66, 32), 256, 0, stream>>>(krw, krx, kry, krz,
                                                    kiw, kix, kiy, kiz, WT);
    fft_fwd_kernel<<<dim3(NIMG/4), 512, 0, stream>>>(x, Xs);
    xpose_x_kernel<<<dim3(128, NBIN/32), 256, 0, stream>>>(Xs, (u32*)XT);
    contract_kernel<<<dim3(NBIN), 256, 0, stream>>>(XT, WT, P);
    pxpose_kernel<<<dim3(NBIN/32, NIMG/32), 256, 0, stream>>>(P, PT);
    fft_inv_kernel<<<dim3(NIMG/4), 512, 0, stream>>>(PT, out);
}

// Round 11
// 112.646 us; speedup vs baseline: 1.8822x; 1.0633x over previous
//
#include <hip/hip_runtime.h>

#define FH 64
#define FW 64
#define NWF 33
#define NBIN (FH*NWF)      // 2112
#define NIMG 4096          // 4 * 32 * 32
#define PI2 6.283185307179586f

typedef unsigned short u16;
typedef unsigned int u32;
typedef __attribute__((ext_vector_type(8))) short bf16x8;
typedef __attribute__((ext_vector_type(8))) _Float16 f16x8;
typedef __attribute__((ext_vector_type(4))) unsigned short u16x4;
typedef __attribute__((ext_vector_type(4))) float f32x4;
typedef __attribute__((ext_vector_type(4))) int   i32x4;

__device__ __forceinline__ u16 f2bf(float f) {
    unsigned u = __float_as_uint(f);
    unsigned r = (u + 0x7FFFu + ((u >> 16) & 1u)) >> 16;   // RNE
    return (u16)r;
}
__device__ __forceinline__ u16 f2h(float f) {
    _Float16 h = (_Float16)f;
    return __builtin_bit_cast(u16, h);
}
__device__ __forceinline__ float2 upk(u32 v) {
    return make_float2(__uint_as_float(v << 16), __uint_as_float(v & 0xFFFF0000u));
}
__device__ __forceinline__ u32 pk(float2 v) {
    return (u32)f2bf(v.x) | ((u32)f2bf(v.y) << 16);
}
__device__ __forceinline__ f16x8 negh(f16x8 v) {
    i32x4 t = __builtin_bit_cast(i32x4, v);
    t ^= (int)0x80008000;
    return __builtin_bit_cast(f16x8, t);
}

// ================= FAT KERNEL: fft_fwd (blocks 0..1023)  ∥  prep_w (blocks 1024..3135) ==========
// Shared smem arena: fwd uses mats (9216 u16) + 4 per-image ST (6912 u16 each) = 36864 u16 = 73.7KB
//                    prep_w uses 32*264 = 8448 u16 of the same arena.
__global__ __launch_bounds__(512, 4) void fwd_prep_kernel(
    const float* __restrict__ x, u32* __restrict__ Xs,
    const float* __restrict__ s0, const float* __restrict__ s1,
    const float* __restrict__ s2, const float* __restrict__ s3,
    const float* __restrict__ s4, const float* __restrict__ s5,
    const float* __restrict__ s6, const float* __restrict__ s7,
    u16* __restrict__ WT)
{
    __shared__ __align__(16) u16 sm[36864];
    const int tid = threadIdx.x;

    if (blockIdx.x < 1024) {
        // ---------------- forward rfft2 via MFMA-DFT: two waves per image ----------------
        const int lane = tid & 63;
        const int wid  = tid >> 6;         // 0..7
        const int slot = wid >> 1;         // image slot 0..3
        const int half = wid & 1;          // M-split half
        const int a16  = lane & 15;
        const int q    = lane >> 4;

        const int img = blockIdx.x * 4 + slot;     // qc*1024 + b*32 + ci
        const int qc = img >> 10;
        const int b  = (img >> 5) & 31;
        const int ci = img & 31;
        const float* __restrict__ src = x + ((size_t)b*128 + (size_t)qc*32 + ci) * (FH*FW);

        u16* mats0 = sm;                   // cos[a*72+b]
        u16* mats1 = sm + 64*72;           // sin[a*72+b]
        u16* ST    = sm + 9216 + slot*6912;

        for (int t = tid; t < 4096; t += 512) {
            int a = t >> 6, bb = t & 63;
            float sn, cs;
            __sincosf(PI2 * (float)((a*bb) & 63) * (1.f/64.f), &sn, &cs);
            mats0[a*72 + bb] = f2h(cs);
            mats1[a*72 + bb] = f2h(sn);
        }

        // A-fragments straight from global (2 lanes per 64B line, lines fully covered)
        f16x8 xf[2][2];
        #pragma unroll
        for (int mtl = 0; mtl < 2; ++mtl)
            #pragma unroll
            for (int ks = 0; ks < 2; ++ks) {
                const float* rp = src + (16*(2*half + mtl) + a16)*64 + ks*32 + q*8;
                float4 v0 = *(const float4*)rp;
                float4 v1 = *(const float4*)(rp + 4);
                xf[mtl][ks] = (f16x8){ (_Float16)v0.x, (_Float16)v0.y, (_Float16)v0.z, (_Float16)v0.w,
                                       (_Float16)v1.x, (_Float16)v1.y, (_Float16)v1.z, (_Float16)v1.w };
            }
        __syncthreads();   // mats ready

        // step1: S_re = x*C, S_im = -x*S; store transposed S_T[ri][k][h], stride 72
        #pragma unroll
        for (int mtl = 0; mtl < 2; ++mtl) {
            const int mt = 2*half + mtl;
            f32x4 are[3], aim[3];
            #pragma unroll
            for (int nt = 0; nt < 3; ++nt) { are[nt] = (f32x4){0,0,0,0}; aim[nt] = (f32x4){0,0,0,0}; }
            #pragma unroll
            for (int nt = 0; nt < 3; ++nt)
                #pragma unroll
                for (int ks = 0; ks < 2; ++ks) {
                    const int rb = (16*nt + a16)*72 + ks*32 + q*8;
                    f16x8 cf = *(const f16x8*)&mats0[rb];
                    f16x8 sf = *(const f16x8*)&mats1[rb];
                    are[nt] = __builtin_amdgcn_mfma_f32_16x16x32_f16(xf[mtl][ks], cf, are[nt], 0, 0, 0);
                    aim[nt] = __builtin_amdgcn_mfma_f32_16x16x32_f16(xf[mtl][ks], negh(sf), aim[nt], 0, 0, 0);
                }
            const int hb = 16*mt + 4*q;
            #pragma unroll
            for (int nt = 0; nt < 3; ++nt) {
                u16x4 re4 = { f2h(are[nt][0]), f2h(are[nt][1]), f2h(are[nt][2]), f2h(are[nt][3]) };
                u16x4 im4 = { f2h(aim[nt][0]), f2h(aim[nt][1]), f2h(aim[nt][2]), f2h(aim[nt][3]) };
                *(u16x4*)&ST[(16*nt + a16)*72 + hb]      = re4;
                *(u16x4*)&ST[(48 + 16*nt + a16)*72 + hb] = im4;
            }
        }
        __syncthreads();   // ST complete (both waves of each image)

        // step2 B-fragments from ST (no further barrier: ST never overwritten)
        f16x8 bfr[2][3][2];
        #pragma unroll
        for (int ri = 0; ri < 2; ++ri)
            #pragma unroll
            for (int nt = 0; nt < 3; ++nt)
                #pragma unroll
                for (int ks = 0; ks < 2; ++ks)
                    bfr[ri][nt][ks] = *(const f16x8*)&ST[(ri*48 + 16*nt + a16)*72 + ks*32 + q*8];

        // step2: X_re = C*S_re + S*S_im ; X_im = C*S_im - S*S_re; direct global store
        u32* __restrict__ dst = Xs + (size_t)img * NBIN;
        #pragma unroll
        for (int mtl = 0; mtl < 2; ++mtl) {
            const int mt = 2*half + mtl;
            f16x8 cfa[2], sfa[2], nsf[2];
            #pragma unroll
            for (int ks = 0; ks < 2; ++ks) {
                const int rb = (16*mt + a16)*72 + ks*32 + q*8;
                cfa[ks] = *(const f16x8*)&mats0[rb];
                sfa[ks] = *(const f16x8*)&mats1[rb];
                nsf[ks] = negh(sfa[ks]);
            }
            #pragma unroll
            for (int nt = 0; nt < 3; ++nt) {
                f32x4 xre = (f32x4){0,0,0,0}, xim = (f32x4){0,0,0,0};
                #pragma unroll
                for (int ks = 0; ks < 2; ++ks) {
                    xre = __builtin_amdgcn_mfma_f32_16x16x32_f16(cfa[ks], bfr[0][nt][ks], xre, 0, 0, 0);
                    xre = __builtin_amdgcn_mfma_f32_16x16x32_f16(sfa[ks], bfr[1][nt][ks], xre, 0, 0, 0);
                    xim = __builtin_amdgcn_mfma_f32_16x16x32_f16(cfa[ks], bfr[1][nt][ks], xim, 0, 0, 0);
                    xim = __builtin_amdgcn_mfma_f32_16x16x32_f16(nsf[ks], bfr[0][nt][ks], xim, 0, 0, 0);
                }
                const int k = 16*nt + a16;     // col of D; row hf = 16mt+4q+r
                if (k < 33) {
                    #pragma unroll
                    for (int r = 0; r < 4; ++r)
                        dst[(16*mt + 4*q + r)*33 + k] = pk(make_float2(xre[r], xim[r]));
                }
            }
        }
    } else {
        // ---------------- transpose W (tiled): [i][o][bin] f32 -> [bin][p][ri][o][i] bf16 --------
        const int pb = blockIdx.x - 1024;   // 0..2111
        const int bt = pb % 66;             // bin tile
        const int ay = pb / 66;             // 0..31
        const int a  = ay >> 2;             // array 0..7 (kr_wxyz, ki_wxyz)
        const int o0 = (ay & 3) * 8;
        const float* __restrict__ src =
            (a==0)?s0:(a==1)?s1:(a==2)?s2:(a==3)?s3:(a==4)?s4:(a==5)?s5:(a==6)?s6:s7;
        const int bin0 = bt * 32;
        u16* lds2 = sm;                     // [binL][chL], stride 264

        #pragma unroll
        for (int it = 0; it < 4; ++it) {
            int e = tid + it*512;           // 2048 float4 tasks
            int f4 = e & 7, rt = e >> 3;
            int i = rt & 31, oo = rt >> 5;
            int io = i*32 + o0 + oo;
            float4 v = ((const float4*)src)[(size_t)io*(NBIN/4) + bt*8 + f4];
            int chL = oo*32 + i;
            int bb = f4*4;
            lds2[(bb+0)*264 + chL] = f2bf(v.x);
            lds2[(bb+1)*264 + chL] = f2bf(v.y);
            lds2[(bb+2)*264 + chL] = f2bf(v.z);
            lds2[(bb+3)*264 + chL] = f2bf(v.w);
        }
        __syncthreads();
        const int p = a & 3, ri = a >> 2;
        #pragma unroll
        for (int it = 0; it < 2; ++it) {
            int e = tid + it*512;           // 1024 bf16x8 tasks
            int binL = e >> 5, c8 = e & 31;
            bf16x8 v = *(const bf16x8*)&lds2[binL*264 + c8*8];
            size_t d = ((size_t)(bin0 + binL)*8 + p*2 + ri)*1024 + o0*32 + c8*8;
            *(bf16x8*)(WT + d) = v;
        }
    }
}

// ---------------- transpose X: [img][bin] u32 -> [bin][q][ri][b][i] bf16 ----------------
__global__ __launch_bounds__(256) void xpose_x_kernel(const u32* __restrict__ Xs,
                                                      u32* __restrict__ XT)
{
    const int g    = blockIdx.x;        // q*32 + b
    const int bin0 = blockIdx.y * 32;
    __shared__ u32 tile[32][33];
    const int tid = threadIdx.x;
    #pragma unroll
    for (int it = 0; it < 4; ++it) {
        int e = tid + it*256;
        int imgL = e >> 5, binL = e & 31;
        tile[imgL][binL] = Xs[(size_t)(g*32 + imgL) * NBIN + bin0 + binL];
    }
    __syncthreads();
    const int q = g >> 5, b = g & 31;
    #pragma unroll
    for (int it = 0; it < 2; ++it) {
        int e = tid + it*256;          // 512 tasks: [binL][i-pair]
        int binL = e >> 4, pr = e & 15;
        u32 v0 = tile[pr*2][binL], v1 = tile[pr*2 + 1][binL];
        u32 re = (v0 & 0xFFFFu) | (v1 << 16);
        u32 im = (v0 >> 16) | (v1 & 0xFFFF0000u);
        size_t base = ((size_t)(bin0 + binL)*8 + q*2) * 512 + b*16 + pr;  // u32 units
        XT[base]       = re;
        XT[base + 512] = im;
    }
}

// ---------------- per-bin quaternion contraction via MFMA ----------------
__global__ __launch_bounds__(256) void contract_kernel(
    const u16* __restrict__ XT, const u16* __restrict__ WT,
    u32* __restrict__ P)
{
    const int bid  = blockIdx.x;
    const int bin  = (bid & 7) * (NBIN/8) + (bid >> 3);   // chunked XCD swizzle
    const int wid  = threadIdx.x >> 6;
    const int lane = threadIdx.x & 63;
    const int bh = wid >> 1, oh = wid & 1;
    const int row = lane & 15, kg = lane >> 4;

    const u16* __restrict__ xb = XT + (size_t)bin * 8192;
    const u16* __restrict__ wb = WT + (size_t)bin * 8192;

    bf16x8 ax[4][2];
    #pragma unroll
    for (int q = 0; q < 4; ++q)
        #pragma unroll
        for (int ri = 0; ri < 2; ++ri)
            ax[q][ri] = *(const bf16x8*)(xb + ((q*2 + ri)*32 + bh*16 + row)*32 + kg*8);

    bf16x8 wpos[4][2], wneg[4][2];
    #pragma unroll
    for (int p = 0; p < 4; ++p)
        #pragma unroll
        for (int ri = 0; ri < 2; ++ri) {
            bf16x8 w = *(const bf16x8*)(wb + ((p*2 + ri)*32 + oh*16 + row)*32 + kg*8);
            wpos[p][ri] = w;
            i32x4 t = __builtin_bit_cast(i32x4, w);
            t ^= (int)0x80008000;
            wneg[p][ri] = __builtin_bit_cast(bf16x8, t);
        }

    f32x4 acc[4][2];
    #pragma unroll
    for (int c = 0; c < 4; ++c)
        #pragma unroll
        for (int ri = 0; ri < 2; ++ri)
            acc[c][ri] = (f32x4){0.f, 0.f, 0.f, 0.f};

    constexpr int PI_[4][4] = {{0,1,2,3},{1,0,3,2},{2,3,0,1},{3,2,1,0}};
    constexpr int SG_[4][4] = {{1,-1,-1,-1},{1,1,-1,1},{1,1,1,-1},{1,-1,1,1}};
    #pragma unroll
    for (int c = 0; c < 4; ++c)
        #pragma unroll
        for (int q = 0; q < 4; ++q) {
            const int  p   = PI_[c][q];
            const bool pos = SG_[c][q] > 0;
            bf16x8 wr_s = pos ? wpos[p][0] : wneg[p][0];
            bf16x8 wi_s = pos ? wpos[p][1] : wneg[p][1];
            bf16x8 wi_m = pos ? wneg[p][1] : wpos[p][1];
            acc[c][0] = __builtin_amdgcn_mfma_f32_16x16x32_bf16(ax[q][0], wr_s, acc[c][0], 0, 0, 0);
            acc[c][0] = __builtin_amdgcn_mfma_f32_16x16x32_bf16(ax[q][1], wi_m, acc[c][0], 0, 0, 0);
            acc[c][1] = __builtin_amdgcn_mfma_f32_16x16x32_bf16(ax[q][1], wr_s, acc[c][1], 0, 0, 0);
            acc[c][1] = __builtin_amdgcn_mfma_f32_16x16x32_bf16(ax[q][0], wi_s, acc[c][1], 0, 0, 0);
        }

    u32* __restrict__ dst = P + (size_t)bin * 4096;
    #pragma unroll
    for (int c = 0; c < 4; ++c)
        #pragma unroll
        for (int r = 0; r < 4; ++r) {
            int b_ = bh*16 + kg*4 + r;
            int o  = oh*16 + row;
            dst[c*1024 + b_*32 + o] = pk(make_float2(acc[c][0][r], acc[c][1][r]));
        }
}

// ---------------- transpose P: [bin][img] u32 -> PT[img][bin] u32 ----------------
__global__ __launch_bounds__(256) void pxpose_kernel(const u32* __restrict__ P,
                                                     u32* __restrict__ PT)
{
    const int bin0 = blockIdx.x * 32;
    const int img0 = blockIdx.y * 32;
    __shared__ u32 tile[32][33];
    const int tid = threadIdx.x;
    #pragma unroll
    for (int it = 0; it < 4; ++it) {
        int e = tid + it*256;
        int bi = e >> 5, im = e & 31;
        tile[bi][im] = P[(size_t)(bin0 + bi) * 4096 + img0 + im];
    }
    __syncthreads();
    #pragma unroll
    for (int it = 0; it < 4; ++it) {
        int e = tid + it*256;
        int im = e >> 5, bi = e & 31;
        PT[(size_t)(img0 + im) * NBIN + bin0 + bi] = tile[bi][im];
    }
}

// ---------------- inverse rfft2 via MFMA-DFT: TWO waves per image ----------------
__global__ __launch_bounds__(512, 4) void fft_inv_kernel(const u32* __restrict__ PT,
                                                         float* __restrict__ out)
{
    __shared__ __align__(16) u16 mats[2][64*72];   // cos/sin(+2pi ab/64), symmetric
    __shared__ __align__(16) u16 wbuf[4][7168];    // per-image: ET (2x48x72) / T (2x64x56)

    const int tid  = threadIdx.x;
    const int lane = tid & 63;
    const int wid  = tid >> 6;
    const int slot = wid >> 1;
    const int half = wid & 1;
    const int ltid = (half << 6) | lane;
    const int a16  = lane & 15;
    const int q    = lane >> 4;

    const int img = blockIdx.x * 4 + slot;         // c*1024 + b*32 + oc
    const int c  = img >> 10;
    const int b  = (img >> 5) & 31;
    const int oc = img & 31;

    for (int t = tid; t < 4096; t += 512) {
        int a = t >> 6, bb = t & 63;
        float sn, cs;
        __sincosf(PI2 * (float)((a*bb) & 63) * (1.f/64.f), &sn, &cs);
        mats[0][a*72 + bb] = f2h(cs);
        mats[1][a*72 + bb] = f2h(sn);
    }

    // stage E^T: ETre[k][hf], ETim[k][hf], stride 72. Rows k=33..47 MUST be zero.
    u16* ETre = wbuf[slot];
    u16* ETim = wbuf[slot] + 48*72;
    for (int j = 33*72 + ltid; j < 48*72; j += 128) {
        ETre[j] = 0;
        ETim[j] = 0;
    }
    const u32* __restrict__ srcP = PT + (size_t)img * NBIN;
    for (int i = 0; i < 17; ++i) {
        int t = i*128 + ltid;
        if (t < NBIN) {
            int hf = t / 33, k = t - hf*33;
            float2 v = upk(srcP[t]);
            ETre[k*72 + hf] = f2h(v.x);
            ETim[k*72 + hf] = f2h(v.y);
        }
    }
    __syncthreads();

    // preload this wave's E^T A-fragments (mt = 2*half + mtl, valid mt < 3)
    f16x8 ere[2][2], eim[2][2];
    #pragma unroll
    for (int mtl = 0; mtl < 2; ++mtl) {
        const int mt = 2*half + mtl;
        if (mt < 3) {
            #pragma unroll
            for (int ks = 0; ks < 2; ++ks) {
                ere[mtl][ks] = *(const f16x8*)&ETre[(16*mt + a16)*72 + ks*32 + q*8];
                eim[mtl][ks] = *(const f16x8*)&ETim[(16*mt + a16)*72 + ks*32 + q*8];
            }
        }
    }
    __syncthreads();

    // step1: T_re^T = Ere*C - Eim*S ; T_im^T = Ere*S + Eim*C; D-layout writes T[h][m]
    u16* Tre = wbuf[slot];             // [64][56]
    u16* Tim = wbuf[slot] + 64*56;
    #pragma unroll
    for (int mtl = 0; mtl < 2; ++mtl) {
        const int mt = 2*half + mtl;
        if (mt < 3) {
            #pragma unroll
            for (int nt = 0; nt < 4; ++nt) {
                f32x4 tre = (f32x4){0,0,0,0}, tim = (f32x4){0,0,0,0};
                #pragma unroll
                for (int ks = 0; ks < 2; ++ks) {
                    const int rb = (16*nt + a16)*72 + ks*32 + q*8;
                    f16x8 cf = *(const f16x8*)&mats[0][rb];
                    f16x8 sf = *(const f16x8*)&mats[1][rb];
                    tre = __builtin_amdgcn_mfma_f32_16x16x32_f16(ere[mtl][ks], cf, tre, 0, 0, 0);
                    tre = __builtin_amdgcn_mfma_f32_16x16x32_f16(eim[mtl][ks], negh(sf), tre, 0, 0, 0);
                    tim = __builtin_amdgcn_mfma_f32_16x16x32_f16(ere[mtl][ks], sf, tim, 0, 0, 0);
                    tim = __builtin_amdgcn_mfma_f32_16x16x32_f16(eim[mtl][ks], cf, tim, 0, 0, 0);
                }
                const int m0 = 16*mt + 4*q;        // row = m, col = h
                u16x4 r4, i4;
                #pragma unroll
                for (int r = 0; r < 4; ++r) {
                    int m = m0 + r;
                    float s = (m == 0 || m == 32) ? (1.f/4096.f) : (2.f/4096.f);
                    r4[r] = (m < 33) ? f2h(tre[r] * s) : (u16)0;
                    i4[r] = (m < 33) ? f2h(tim[r] * s) : (u16)0;
                }
                *(u16x4*)&Tre[(16*nt + a16)*56 + m0] = r4;
                *(u16x4*)&Tim[(16*nt + a16)*56 + m0] = i4;
            }
        }
    }
    __syncthreads();

    // step2: out[h][w] = sum_m Tre[h][m]*C[w][m] - Tim[h][m]*S[w][m]
    float* __restrict__ dst = out + ((size_t)b*128 + (size_t)c*32 + oc) * (FH*FW);
    #pragma unroll
    for (int mtl = 0; mtl < 2; ++mtl) {
        const int mt = 2*half + mtl;
        f16x8 tfr[2], tfi[2];
        #pragma unroll
        for (int ks = 0; ks < 2; ++ks) {
            const int mbase = ks*32 + q*8;
            if (mbase < 48) {
                tfr[ks] = *(const f16x8*)&Tre[(16*mt + a16)*56 + mbase];
                tfi[ks] = *(const f16x8*)&Tim[(16*mt + a16)*56 + mbase];
            } else {
                tfr[ks] = (f16x8){0,0,0,0,0,0,0,0};
                tfi[ks] = (f16x8){0,0,0,0,0,0,0,0};
            }
        }
        #pragma unroll
        for (int nt = 0; nt < 4; ++nt) {
            f32x4 acc = (f32x4){0,0,0,0};
            #pragma unroll
            for (int ks = 0; ks < 2; ++ks) {
                const int rb = (16*nt + a16)*72 + ks*32 + q*8;
                f16x8 cf = *(const f16x8*)&mats[0][rb];
                f16x8 sf = *(const f16x8*)&mats[1][rb];
                acc = __builtin_amdgcn_mfma_f32_16x16x32_f16(tfr[ks], cf, acc, 0, 0, 0);
                acc = __builtin_amdgcn_mfma_f32_16x16x32_f16(tfi[ks], negh(sf), acc, 0, 0, 0);
            }
            // col = w = 16nt+a16, row = h = 16mt+4q+r
            #pragma unroll
            for (int r = 0; r < 4; ++r)
                dst[(16*mt + 4*q + r)*64 + 16*nt + a16] = acc[r];
        }
    }
}

extern "C" void kernel_launch(void* const* d_in, const int* in_sizes, int n_in,
                              void* d_out, int out_size, void* d_ws, size_t ws_size,
                              hipStream_t stream)
{
    const float* x   = (const float*)d_in[0];
    const float* krw = (const float*)d_in[1];
    const float* krx = (const float*)d_in[2];
    const float* kry = (const float*)d_in[3];
    const float* krz = (const float*)d_in[4];
    const float* kiw = (const float*)d_in[5];
    const float* kix = (const float*)d_in[6];
    const float* kiy = (const float*)d_in[7];
    const float* kiz = (const float*)d_in[8];

    // ws regions (34.6 MB each): [XT / PT] [WT] [Xs / P]
    const size_t R = (size_t)NBIN * 8192 * sizeof(u16);   // 34.6 MB
    u16* XT = (u16*)d_ws;
    u32* PT = (u32*)d_ws;                                  // alias: XT dead after contract
    u16* WT = (u16*)((char*)d_ws + R);
    u32* Xs = (u32*)((char*)d_ws + 2*R);
    u32* P  = Xs;                                          // alias: Xs dead after xpose
    float* out = (float*)d_out;

    fwd_prep_kernel<<<dim3(1024 + 2112), 512, 0, stream>>>(x, Xs,
                                                           krw, krx, kry, krz,
                                                           kiw, kix, kiy, kiz, WT);
    xpose_x_kernel<<<dim3(128, NBIN/32), 256, 0, stream>>>(Xs, (u32*)XT);
    contract_kernel<<<dim3(NBIN), 256, 0, stream>>>(XT, WT, P);
    pxpose_kernel<<<dim3(NBIN/32, NIMG/32), 256, 0, stream>>>(P, PT);
    fft_inv_kernel<<<dim3(NIMG/4), 512, 0, stream>>>(PT, out);
}